// Round 1
// baseline (1523.306 us; speedup 1.0000x reference)
//
#include <hip/hip_runtime.h>

// GCN: 100K nodes, 1.6M edges, 128 -> 128 -> 128 -> 64
// Strategy: build CSR (by dst) once per call, then per layer:
//   GEMM (fp32 vector FMA, W in LDS) -> fused gather-aggregate + norm + bias (+relu)

#define NN 100000
#define NE 1600000
#define TT (NE + NN)   // edges + self loops

// ---------------- CSR build ----------------

__global__ void count_deg(const int* __restrict__ ei, int* __restrict__ deg) {
    int t = blockIdx.x * blockDim.x + threadIdx.x;
    if (t >= TT) return;
    int d = (t < NE) ? ei[NE + t] : (t - NE);   // ei[1][e] = dst; self loop dst = v
    atomicAdd(&deg[d], 1);
}

// single block, 1024 threads: exclusive scan of deg -> rowptr, cursor; dinv = rsqrt(deg)
__global__ __launch_bounds__(1024) void scan_deg(const int* __restrict__ deg,
                                                 int* __restrict__ rowptr,
                                                 int* __restrict__ cursor,
                                                 float* __restrict__ dinv) {
    __shared__ int sums[1024];
    const int t = threadIdx.x;
    const int C = (NN + 1023) / 1024;   // 98
    const int base = t * C;
    const int end = (base + C < NN) ? base + C : NN;
    int s = 0;
    for (int i = base; i < end; i++) s += deg[i];
    sums[t] = s;
    __syncthreads();
    // Hillis-Steele inclusive scan
    for (int off = 1; off < 1024; off <<= 1) {
        int v = (t >= off) ? sums[t - off] : 0;
        __syncthreads();
        sums[t] += v;
        __syncthreads();
    }
    int run = sums[t] - s;   // exclusive prefix
    for (int i = base; i < end; i++) {
        int d = deg[i];
        rowptr[i] = run;
        cursor[i] = run;
        dinv[i] = rsqrtf((float)d);   // deg >= 1 always (self loop)
        run += d;
    }
    if (t == 1023) rowptr[NN] = sums[1023];
}

__global__ void fill_csr(const int* __restrict__ ei, int* __restrict__ cursor,
                         const float* __restrict__ dinv,
                         int* __restrict__ col, float* __restrict__ wgt) {
    int t = blockIdx.x * blockDim.x + threadIdx.x;
    if (t >= TT) return;
    int s, d;
    if (t < NE) { s = ei[t]; d = ei[NE + t]; }
    else        { s = d = t - NE; }
    int pos = atomicAdd(&cursor[d], 1);
    col[pos] = s;
    wgt[pos] = dinv[s];   // norm = dinv[src]*dinv[dst]; dinv[dst] applied at aggregate
}

// ---------------- GEMM: Y[N x F] = X[N x 128] @ W[128 x F] ----------------
// 256 threads, 32 rows x F cols per block. W fully resident in LDS.

__device__ __forceinline__ float f4c(const float4& v, int k) {
    return k == 0 ? v.x : k == 1 ? v.y : k == 2 ? v.z : v.w;
}

template <int F>
__global__ __launch_bounds__(256) void gemm_x(const float* __restrict__ X,
                                              const float* __restrict__ W,
                                              float* __restrict__ Y) {
    constexpr int CPT = F / 32;   // cols per thread (4 or 2)
    __shared__ float Wlds[128 * F];
    for (int i = threadIdx.x; i < (128 * F) / 4; i += 256)
        reinterpret_cast<float4*>(Wlds)[i] = reinterpret_cast<const float4*>(W)[i];
    __syncthreads();

    const int tx = threadIdx.x & 31;
    const int ty = threadIdx.x >> 5;
    const int row0 = blockIdx.x * 32 + ty * 4;

    float acc[4][CPT];
#pragma unroll
    for (int i = 0; i < 4; i++)
#pragma unroll
        for (int j = 0; j < CPT; j++) acc[i][j] = 0.f;

    const float* xp = X + (size_t)row0 * 128;
#pragma unroll 2
    for (int k0 = 0; k0 < 128; k0 += 4) {
        float4 xr[4];
#pragma unroll
        for (int i = 0; i < 4; i++)
            xr[i] = *reinterpret_cast<const float4*>(xp + i * 128 + k0);
#pragma unroll
        for (int kk = 0; kk < 4; kk++) {
            float wv[CPT];
#pragma unroll
            for (int j = 0; j < CPT; j++)
                wv[j] = Wlds[(k0 + kk) * F + tx * CPT + j];
#pragma unroll
            for (int i = 0; i < 4; i++) {
                float xv = f4c(xr[i], kk);
#pragma unroll
                for (int j = 0; j < CPT; j++) acc[i][j] += xv * wv[j];
            }
        }
    }
#pragma unroll
    for (int i = 0; i < 4; i++) {
        float* yp = Y + (size_t)(row0 + i) * F + tx * CPT;
        if constexpr (CPT == 4) {
            *reinterpret_cast<float4*>(yp) =
                make_float4(acc[i][0], acc[i][1], acc[i][2], acc[i][3]);
        } else {
            *reinterpret_cast<float2*>(yp) = make_float2(acc[i][0], acc[i][1]);
        }
    }
}

// ---------------- Aggregate: out[v] = dinv[v] * sum_e wgt[e]*XW[col[e]] + b ----------------

template <int F, bool RELU>
__global__ __launch_bounds__(256) void aggregate(const float* __restrict__ XW,
                                                 const int* __restrict__ rowptr,
                                                 const int* __restrict__ col,
                                                 const float* __restrict__ wgt,
                                                 const float* __restrict__ dinv,
                                                 const float* __restrict__ bias,
                                                 float* __restrict__ out) {
    constexpr int NPB = 256 / F;   // nodes per block
    const int v = blockIdx.x * NPB + threadIdx.x / F;
    const int f = threadIdx.x & (F - 1);
    if (v >= NN) return;
    const int beg = rowptr[v];
    const int end = rowptr[v + 1];
    float acc = 0.f;
    for (int e = beg; e < end; e++) {
        int u = col[e];
        float w = wgt[e];
        acc += w * XW[(size_t)u * F + f];
    }
    float r = dinv[v] * acc + bias[f];
    if (RELU) r = fmaxf(r, 0.f);
    out[(size_t)v * F + f] = r;
}

// ---------------- launch ----------------

extern "C" void kernel_launch(void* const* d_in, const int* in_sizes, int n_in,
                              void* d_out, int out_size, void* d_ws, size_t ws_size,
                              hipStream_t stream) {
    const float* x  = (const float*)d_in[0];
    const int*   ei = (const int*)d_in[1];
    const float* W1 = (const float*)d_in[2];
    const float* b1 = (const float*)d_in[3];
    const float* W2 = (const float*)d_in[4];
    const float* b2 = (const float*)d_in[5];
    const float* W3 = (const float*)d_in[6];
    const float* b3 = (const float*)d_in[7];
    float* out = (float*)d_out;

    // workspace carve (all 16B-aligned)
    char* p = (char*)d_ws;
    int*   deg    = (int*)p;            p += 400000;           // NN*4
    int*   rowptr = (int*)p;            p += 400016;           // (NN+1)*4 padded
    int*   cursor = (int*)p;            p += 400000;
    float* dinv   = (float*)p;          p += 400000;
    int*   col    = (int*)p;            p += (size_t)TT * 4;   // 6.8 MB
    float* wgt    = (float*)p;          p += (size_t)TT * 4;   // 6.8 MB
    float* xw     = (float*)p;          p += (size_t)NN * 128 * 4;   // 51.2 MB
    float* h      = (float*)p;          // 51.2 MB

    hipMemsetAsync(deg, 0, (size_t)NN * 4, stream);
    count_deg<<<(TT + 255) / 256, 256, 0, stream>>>(ei, deg);
    scan_deg<<<1, 1024, 0, stream>>>(deg, rowptr, cursor, dinv);
    fill_csr<<<(TT + 255) / 256, 256, 0, stream>>>(ei, cursor, dinv, col, wgt);

    // layer 1: xw = x@W1 ; h = relu(agg(xw) + b1)
    gemm_x<128><<<NN / 32, 256, 0, stream>>>(x, W1, xw);
    aggregate<128, true><<<NN / 2, 256, 0, stream>>>(xw, rowptr, col, wgt, dinv, b1, h);
    // layer 2
    gemm_x<128><<<NN / 32, 256, 0, stream>>>(h, W2, xw);
    aggregate<128, true><<<NN / 2, 256, 0, stream>>>(xw, rowptr, col, wgt, dinv, b2, h);
    // layer 3 (64-wide, no relu) -> d_out
    gemm_x<64><<<NN / 32, 256, 0, stream>>>(h, W3, xw);
    aggregate<64, false><<<NN / 4, 256, 0, stream>>>(xw, rowptr, col, wgt, dinv, b3, out);
}

// Round 2
// 1101.925 us; speedup vs baseline: 1.3824x; 1.3824x over previous
//
#include <hip/hip_runtime.h>

// GCN: 100K nodes, 1.6M edges, 128 -> 128 -> 128 -> 64 (fp32)
// CSR by dst (once per call) -> per layer: tiled GEMM -> fused gather-aggregate.

#define NN 100000
#define NE 1600000
#define TT (NE + NN)   // edges + self loops

// ---------------- CSR build ----------------

__global__ void count_deg(const int* __restrict__ ei, int* __restrict__ deg) {
    int t = blockIdx.x * blockDim.x + threadIdx.x;
    if (t >= TT) return;
    int d = (t < NE) ? ei[NE + t] : (t - NE);
    atomicAdd(&deg[d], 1);
}

// single block: exclusive scan deg -> rowptr/cursor, dinv = rsqrt(deg)
__global__ __launch_bounds__(1024) void scan_deg(const int* __restrict__ deg,
                                                 int* __restrict__ rowptr,
                                                 int* __restrict__ cursor,
                                                 float* __restrict__ dinv) {
    __shared__ int sums[1024];
    const int t = threadIdx.x;
    const int C = (NN + 1023) / 1024;   // 98
    const int base = t * C;
    const int end = (base + C < NN) ? base + C : NN;
    int s = 0;
    for (int i = base; i < end; i++) s += deg[i];
    sums[t] = s;
    __syncthreads();
    for (int off = 1; off < 1024; off <<= 1) {
        int v = (t >= off) ? sums[t - off] : 0;
        __syncthreads();
        sums[t] += v;
        __syncthreads();
    }
    int run = sums[t] - s;
    for (int i = base; i < end; i++) {
        int d = deg[i];
        rowptr[i] = run;
        cursor[i] = run;
        dinv[i] = rsqrtf((float)d);
        run += d;
    }
    if (t == 1023) rowptr[NN] = sums[1023];
}

// edge record: {src, bits(dinv[src])} packed for one 8B load in the gather
__global__ void fill_csr(const int* __restrict__ ei, int* __restrict__ cursor,
                         const float* __restrict__ dinv, int2* __restrict__ cw) {
    int t = blockIdx.x * blockDim.x + threadIdx.x;
    if (t >= TT) return;
    int s, d;
    if (t < NE) { s = ei[t]; d = ei[NE + t]; }
    else        { s = d = t - NE; }
    int pos = atomicAdd(&cursor[d], 1);
    cw[pos] = make_int2(s, __float_as_int(dinv[s]));
}

// ---------------- GEMM: Y[N x F] = X[N x 128] @ W[128 x F] ----------------
// 128 x F block tile, K chunks of 32. X transposed in LDS (Xl[k][row]),
// W row-major in LDS. 8x(F/16) register tile per thread, all b128 LDS reads.

template <int F>
__global__ __launch_bounds__(256) void gemm_tile(const float* __restrict__ X,
                                                 const float* __restrict__ W,
                                                 float* __restrict__ Y) {
    constexpr int TN = (F == 128) ? 8 : 4;
    constexpr int WPAD = F + 4;
    __shared__ float Xl[32][132];        // [k][row], pad 132 keeps 16B align, breaks conflicts
    __shared__ float Wl[32][WPAD];       // [k][col]

    const int tid = threadIdx.x;
    const int wave = tid >> 6;
    const int lane = tid & 63;
    const int wrow = (wave & 1) * 64;
    const int wcol = (wave >> 1) * (F / 2);
    const int r0 = wrow + (lane & 7) * 8;         // local rows r0..r0+7
    const int c0 = wcol + (lane >> 3) * TN;       // local cols c0..c0+TN-1
    const int grow0 = blockIdx.x * 128;

    float acc[8][TN];
#pragma unroll
    for (int i = 0; i < 8; i++)
#pragma unroll
        for (int j = 0; j < TN; j++) acc[i][j] = 0.f;

    const int kgX = tid & 7;     // which float4 along k
    const int rrX = tid >> 3;    // 0..31

    for (int kt = 0; kt < 128; kt += 32) {
        // stage X (transposed) : 128 rows x 32 k
#pragma unroll
        for (int p = 0; p < 4; p++) {
            int row = rrX + 32 * p;
            int gr = grow0 + row;
            float4 xv = make_float4(0.f, 0.f, 0.f, 0.f);
            if (gr < NN)
                xv = *reinterpret_cast<const float4*>(X + (size_t)gr * 128 + kt + kgX * 4);
            Xl[kgX * 4 + 0][row] = xv.x;
            Xl[kgX * 4 + 1][row] = xv.y;
            Xl[kgX * 4 + 2][row] = xv.z;
            Xl[kgX * 4 + 3][row] = xv.w;
        }
        // stage W : 32 k-rows x F cols
        {
            constexpr int GP = F / 4;            // float4 per W row
            int cg = tid % GP;
            int kr = tid / GP;
#pragma unroll
            for (int p = 0; p < (32 * GP) / 256; p++) {
                int k = kr + p * (256 / GP);
                float4 wv = *reinterpret_cast<const float4*>(W + (size_t)(kt + k) * F + cg * 4);
                *reinterpret_cast<float4*>(&Wl[k][cg * 4]) = wv;
            }
        }
        __syncthreads();
#pragma unroll
        for (int k = 0; k < 32; k++) {
            float a[8], b[TN];
            *reinterpret_cast<float4*>(&a[0]) = *reinterpret_cast<float4*>(&Xl[k][r0]);
            *reinterpret_cast<float4*>(&a[4]) = *reinterpret_cast<float4*>(&Xl[k][r0 + 4]);
            *reinterpret_cast<float4*>(&b[0]) = *reinterpret_cast<float4*>(&Wl[k][c0]);
            if constexpr (TN == 8)
                *reinterpret_cast<float4*>(&b[4]) = *reinterpret_cast<float4*>(&Wl[k][c0 + 4]);
#pragma unroll
            for (int i = 0; i < 8; i++)
#pragma unroll
                for (int j = 0; j < TN; j++) acc[i][j] += a[i] * b[j];
        }
        __syncthreads();
    }
#pragma unroll
    for (int i = 0; i < 8; i++) {
        int gr = grow0 + r0 + i;
        if (gr < NN) {
            float* yp = Y + (size_t)gr * F + c0;
            *reinterpret_cast<float4*>(yp) = make_float4(acc[i][0], acc[i][1], acc[i][2], acc[i][3]);
            if constexpr (TN == 8)
                *reinterpret_cast<float4*>(yp + 4) =
                    make_float4(acc[i][4], acc[i][5], acc[i][6], acc[i][7]);
        }
    }
}

// ---------------- Aggregate: out[v] = dinv[v]*sum_e wgt[e]*XW[col[e]] + b ----------------
// float4 per lane: F/4 threads per node, one 16B gather per edge per lane.

template <int F, bool RELU>
__global__ __launch_bounds__(256) void aggregate4(const float4* __restrict__ XW,
                                                  const int* __restrict__ rowptr,
                                                  const int2* __restrict__ cw,
                                                  const float* __restrict__ dinv,
                                                  const float4* __restrict__ bias,
                                                  float4* __restrict__ out) {
    constexpr int TPN = F / 4;        // 32 (F=128) or 16 (F=64)
    constexpr int NPB = 256 / TPN;    // nodes per block
    const int v = blockIdx.x * NPB + threadIdx.x / TPN;
    const int f4 = threadIdx.x % TPN;
    const int beg = rowptr[v];
    const int end = rowptr[v + 1];
    float4 acc = make_float4(0.f, 0.f, 0.f, 0.f);
#pragma unroll 4
    for (int e = beg; e < end; e++) {
        int2 c = cw[e];
        float w = __int_as_float(c.y);
        float4 xv = XW[(size_t)c.x * TPN + f4];
        acc.x += w * xv.x;
        acc.y += w * xv.y;
        acc.z += w * xv.z;
        acc.w += w * xv.w;
    }
    float dv = dinv[v];
    float4 b = bias[f4];
    float4 r = make_float4(dv * acc.x + b.x, dv * acc.y + b.y,
                           dv * acc.z + b.z, dv * acc.w + b.w);
    if (RELU) {
        r.x = fmaxf(r.x, 0.f); r.y = fmaxf(r.y, 0.f);
        r.z = fmaxf(r.z, 0.f); r.w = fmaxf(r.w, 0.f);
    }
    out[(size_t)v * TPN + f4] = r;
}

// ---------------- launch ----------------

extern "C" void kernel_launch(void* const* d_in, const int* in_sizes, int n_in,
                              void* d_out, int out_size, void* d_ws, size_t ws_size,
                              hipStream_t stream) {
    const float* x  = (const float*)d_in[0];
    const int*   ei = (const int*)d_in[1];
    const float* W1 = (const float*)d_in[2];
    const float* b1 = (const float*)d_in[3];
    const float* W2 = (const float*)d_in[4];
    const float* b2 = (const float*)d_in[5];
    const float* W3 = (const float*)d_in[6];
    const float* b3 = (const float*)d_in[7];
    float* out = (float*)d_out;

    char* p = (char*)d_ws;
    int*   deg    = (int*)p;   p += 400000;
    int*   rowptr = (int*)p;   p += 400016;
    int*   cursor = (int*)p;   p += 400000;
    float* dinv   = (float*)p; p += 400000;
    int2*  cw     = (int2*)p;  p += (size_t)TT * 8;           // 13.6 MB
    float* xw     = (float*)p; p += (size_t)NN * 128 * 4;     // 51.2 MB
    float* h      = (float*)p;                                 // 51.2 MB

    hipMemsetAsync(deg, 0, (size_t)NN * 4, stream);
    count_deg<<<(TT + 255) / 256, 256, 0, stream>>>(ei, deg);
    scan_deg<<<1, 1024, 0, stream>>>(deg, rowptr, cursor, dinv);
    fill_csr<<<(TT + 255) / 256, 256, 0, stream>>>(ei, cursor, dinv, cw);

    const int gb = (NN + 127) / 128;   // 782
    // layer 1
    gemm_tile<128><<<gb, 256, 0, stream>>>(x, W1, xw);
    aggregate4<128, true><<<NN / 2 / 4, 256, 0, stream>>>(
        (const float4*)xw, rowptr, cw, dinv, (const float4*)b1, (float4*)h);
    // layer 2
    gemm_tile<128><<<gb, 256, 0, stream>>>(h, W2, xw);
    aggregate4<128, true><<<NN / 2 / 4, 256, 0, stream>>>(
        (const float4*)xw, rowptr, cw, dinv, (const float4*)b2, (float4*)h);
    // layer 3 (no relu) -> d_out
    gemm_tile<64><<<gb, 256, 0, stream>>>(h, W3, xw);
    aggregate4<64, false><<<NN / 4 / 4, 256, 0, stream>>>(
        (const float4*)xw, rowptr, cw, dinv, (const float4*)b3, (float4*)out);
}

// Round 3
// 847.348 us; speedup vs baseline: 1.7977x; 1.3004x over previous
//
#include <hip/hip_runtime.h>

// GCN: 100K nodes, 1.6M edges, 128 -> 128 -> 128 -> 64 (fp32)
// CSR by dst (once per call) -> per layer: tiled GEMM -> fused gather-aggregate.

#define NN 100000
#define NE 1600000
#define TT (NE + NN)   // edges + self loops
#define NBLK ((NN + 255) / 256)   // 391 scan blocks

// ---------------- CSR build ----------------

__global__ void count_deg(const int* __restrict__ ei, int* __restrict__ deg) {
    int t = blockIdx.x * blockDim.x + threadIdx.x;
    if (t >= TT) return;
    int d = (t < NE) ? ei[NE + t] : (t - NE);
    atomicAdd(&deg[d], 1);
}

// multi-block exclusive scan of deg -> rowptr/cursor, dinv = rsqrt(deg)
__global__ __launch_bounds__(256) void block_sums(const int* __restrict__ deg,
                                                  int* __restrict__ bsum) {
    int i = blockIdx.x * 256 + threadIdx.x;
    int d = (i < NN) ? deg[i] : 0;
#pragma unroll
    for (int off = 32; off > 0; off >>= 1) d += __shfl_down(d, off, 64);
    __shared__ int ws[4];
    if ((threadIdx.x & 63) == 0) ws[threadIdx.x >> 6] = d;
    __syncthreads();
    if (threadIdx.x == 0) bsum[blockIdx.x] = ws[0] + ws[1] + ws[2] + ws[3];
}

__global__ __launch_bounds__(512) void scan_bsum(const int* __restrict__ bsum,
                                                 int* __restrict__ bscan) {
    __shared__ int s[512];
    const int t = threadIdx.x;
    int v = (t < NBLK) ? bsum[t] : 0;
    s[t] = v;
    __syncthreads();
    for (int off = 1; off < 512; off <<= 1) {
        int u = (t >= off) ? s[t - off] : 0;
        __syncthreads();
        s[t] += u;
        __syncthreads();
    }
    if (t < NBLK) bscan[t] = s[t] - v;   // exclusive
}

__global__ __launch_bounds__(256) void scan_apply(const int* __restrict__ deg,
                                                  const int* __restrict__ bscan,
                                                  int* __restrict__ rowptr,
                                                  int* __restrict__ cursor,
                                                  float* __restrict__ dinv) {
    __shared__ int s[256];
    const int t = threadIdx.x;
    const int i = blockIdx.x * 256 + t;
    int d = (i < NN) ? deg[i] : 0;
    s[t] = d;
    __syncthreads();
    for (int off = 1; off < 256; off <<= 1) {
        int u = (t >= off) ? s[t - off] : 0;
        __syncthreads();
        s[t] += u;
        __syncthreads();
    }
    int excl = s[t] - d + bscan[blockIdx.x];
    if (i < NN) {
        rowptr[i] = excl;
        cursor[i] = excl;
        dinv[i] = rsqrtf((float)d);
        if (i == NN - 1) rowptr[NN] = excl + d;
    }
}

// edge record: {src, bits(dinv[src])} packed for one 8B load in the gather
__global__ void fill_csr(const int* __restrict__ ei, int* __restrict__ cursor,
                         const float* __restrict__ dinv, int2* __restrict__ cw) {
    int t = blockIdx.x * blockDim.x + threadIdx.x;
    if (t >= TT) return;
    int s, d;
    if (t < NE) { s = ei[t]; d = ei[NE + t]; }
    else        { s = d = t - NE; }
    int pos = atomicAdd(&cursor[d], 1);
    cw[pos] = make_int2(s, __float_as_int(dinv[s]));
}

// ---------------- GEMM: Y[N x F] = X[N x 128] @ W[128 x F] ----------------
// 128 x F block tile, K chunks of 32. X transposed in LDS (Xl[k][row]),
// W row-major in LDS. 8x(F/16) register tile per thread, all b128 LDS reads.

template <int F>
__global__ __launch_bounds__(256) void gemm_tile(const float* __restrict__ X,
                                                 const float* __restrict__ W,
                                                 float* __restrict__ Y) {
    constexpr int TN = (F == 128) ? 8 : 4;
    constexpr int WPAD = F + 4;
    __shared__ float Xl[32][132];
    __shared__ float Wl[32][WPAD];

    const int tid = threadIdx.x;
    const int wave = tid >> 6;
    const int lane = tid & 63;
    const int wrow = (wave & 1) * 64;
    const int wcol = (wave >> 1) * (F / 2);
    const int r0 = wrow + (lane & 7) * 8;
    const int c0 = wcol + (lane >> 3) * TN;
    const int grow0 = blockIdx.x * 128;

    float acc[8][TN];
#pragma unroll
    for (int i = 0; i < 8; i++)
#pragma unroll
        for (int j = 0; j < TN; j++) acc[i][j] = 0.f;

    const int kgX = tid & 7;
    const int rrX = tid >> 3;

    for (int kt = 0; kt < 128; kt += 32) {
#pragma unroll
        for (int p = 0; p < 4; p++) {
            int row = rrX + 32 * p;
            int gr = grow0 + row;
            float4 xv = make_float4(0.f, 0.f, 0.f, 0.f);
            if (gr < NN)
                xv = *reinterpret_cast<const float4*>(X + (size_t)gr * 128 + kt + kgX * 4);
            Xl[kgX * 4 + 0][row] = xv.x;
            Xl[kgX * 4 + 1][row] = xv.y;
            Xl[kgX * 4 + 2][row] = xv.z;
            Xl[kgX * 4 + 3][row] = xv.w;
        }
        {
            constexpr int GP = F / 4;
            int cg = tid % GP;
            int kr = tid / GP;
#pragma unroll
            for (int p = 0; p < (32 * GP) / 256; p++) {
                int k = kr + p * (256 / GP);
                float4 wv = *reinterpret_cast<const float4*>(W + (size_t)(kt + k) * F + cg * 4);
                *reinterpret_cast<float4*>(&Wl[k][cg * 4]) = wv;
            }
        }
        __syncthreads();
#pragma unroll
        for (int k = 0; k < 32; k++) {
            float a[8], b[TN];
            *reinterpret_cast<float4*>(&a[0]) = *reinterpret_cast<float4*>(&Xl[k][r0]);
            *reinterpret_cast<float4*>(&a[4]) = *reinterpret_cast<float4*>(&Xl[k][r0 + 4]);
            *reinterpret_cast<float4*>(&b[0]) = *reinterpret_cast<float4*>(&Wl[k][c0]);
            if constexpr (TN == 8)
                *reinterpret_cast<float4*>(&b[4]) = *reinterpret_cast<float4*>(&Wl[k][c0 + 4]);
#pragma unroll
            for (int i = 0; i < 8; i++)
#pragma unroll
                for (int j = 0; j < TN; j++) acc[i][j] += a[i] * b[j];
        }
        __syncthreads();
    }
#pragma unroll
    for (int i = 0; i < 8; i++) {
        int gr = grow0 + r0 + i;
        if (gr < NN) {
            float* yp = Y + (size_t)gr * F + c0;
            *reinterpret_cast<float4*>(yp) = make_float4(acc[i][0], acc[i][1], acc[i][2], acc[i][3]);
            if constexpr (TN == 8)
                *reinterpret_cast<float4*>(yp + 4) =
                    make_float4(acc[i][4], acc[i][5], acc[i][6], acc[i][7]);
        }
    }
}

// ---------------- Aggregate: out[v] = dinv[v]*sum_e wgt[e]*XW[col[e]] + b ----------------

template <int F, bool RELU>
__global__ __launch_bounds__(256) void aggregate4(const float4* __restrict__ XW,
                                                  const int* __restrict__ rowptr,
                                                  const int2* __restrict__ cw,
                                                  const float* __restrict__ dinv,
                                                  const float4* __restrict__ bias,
                                                  float4* __restrict__ out) {
    constexpr int TPN = F / 4;
    constexpr int NPB = 256 / TPN;
    const int v = blockIdx.x * NPB + threadIdx.x / TPN;
    const int f4 = threadIdx.x % TPN;
    const int beg = rowptr[v];
    const int end = rowptr[v + 1];
    float4 acc = make_float4(0.f, 0.f, 0.f, 0.f);
#pragma unroll 4
    for (int e = beg; e < end; e++) {
        int2 c = cw[e];
        float w = __int_as_float(c.y);
        float4 xv = XW[(size_t)c.x * TPN + f4];
        acc.x += w * xv.x;
        acc.y += w * xv.y;
        acc.z += w * xv.z;
        acc.w += w * xv.w;
    }
    float dv = dinv[v];
    float4 b = bias[f4];
    float4 r = make_float4(dv * acc.x + b.x, dv * acc.y + b.y,
                           dv * acc.z + b.z, dv * acc.w + b.w);
    if (RELU) {
        r.x = fmaxf(r.x, 0.f); r.y = fmaxf(r.y, 0.f);
        r.z = fmaxf(r.z, 0.f); r.w = fmaxf(r.w, 0.f);
    }
    out[(size_t)v * TPN + f4] = r;
}

// ---------------- launch ----------------

extern "C" void kernel_launch(void* const* d_in, const int* in_sizes, int n_in,
                              void* d_out, int out_size, void* d_ws, size_t ws_size,
                              hipStream_t stream) {
    const float* x  = (const float*)d_in[0];
    const int*   ei = (const int*)d_in[1];
    const float* W1 = (const float*)d_in[2];
    const float* b1 = (const float*)d_in[3];
    const float* W2 = (const float*)d_in[4];
    const float* b2 = (const float*)d_in[5];
    const float* W3 = (const float*)d_in[6];
    const float* b3 = (const float*)d_in[7];
    float* out = (float*)d_out;

    char* p = (char*)d_ws;
    int*   deg    = (int*)p;   p += 400000;
    int*   rowptr = (int*)p;   p += 400016;
    int*   cursor = (int*)p;   p += 400000;
    float* dinv   = (float*)p; p += 400000;
    int*   bsum   = (int*)p;   p += 1600;     // NBLK=391 padded
    int*   bscan  = (int*)p;   p += 1600;
    int2*  cw     = (int2*)p;  p += (size_t)TT * 8;        // 13.6 MB
    float* xw     = (float*)p; p += (size_t)NN * 128 * 4;  // 51.2 MB
    float* h      = (float*)p;                              // 51.2 MB

    hipMemsetAsync(deg, 0, (size_t)NN * 4, stream);
    count_deg<<<(TT + 255) / 256, 256, 0, stream>>>(ei, deg);
    block_sums<<<NBLK, 256, 0, stream>>>(deg, bsum);
    scan_bsum<<<1, 512, 0, stream>>>(bsum, bscan);
    scan_apply<<<NBLK, 256, 0, stream>>>(deg, bscan, rowptr, cursor, dinv);
    fill_csr<<<(TT + 255) / 256, 256, 0, stream>>>(ei, cursor, dinv, cw);

    const int gb = (NN + 127) / 128;   // 782
    // layer 1
    gemm_tile<128><<<gb, 256, 0, stream>>>(x, W1, xw);
    aggregate4<128, true><<<NN / 2 / 4, 256, 0, stream>>>(
        (const float4*)xw, rowptr, cw, dinv, (const float4*)b1, (float4*)h);
    // layer 2
    gemm_tile<128><<<gb, 256, 0, stream>>>(h, W2, xw);
    aggregate4<128, true><<<NN / 2 / 4, 256, 0, stream>>>(
        (const float4*)xw, rowptr, cw, dinv, (const float4*)b2, (float4*)h);
    // layer 3 (no relu) -> d_out
    gemm_tile<64><<<gb, 256, 0, stream>>>(h, W3, xw);
    aggregate4<64, false><<<NN / 4 / 4, 256, 0, stream>>>(
        (const float4*)xw, rowptr, cw, dinv, (const float4*)b3, (float4*)out);
}

// Round 4
// 623.214 us; speedup vs baseline: 2.4443x; 1.3596x over previous
//
#include <hip/hip_runtime.h>
#include <hip/hip_fp16.h>

// GCN: 100K nodes, 1.6M edges, 128 -> 128 -> 128 -> 64 (fp32 in/out)
// CSR by dst (once per call) -> per layer: tiled GEMM (fp32 acc, fp16 out)
// -> fused gather-aggregate (fp16 gather, fp32 accumulate).

#define NN 100000
#define NE 1600000
#define TT (NE + NN)   // edges + self loops
#define NBLK ((NN + 255) / 256)   // 391 scan blocks

// ---------------- CSR build ----------------

__global__ void count_deg(const int* __restrict__ ei, int* __restrict__ deg) {
    int t = blockIdx.x * blockDim.x + threadIdx.x;
    if (t >= TT) return;
    int d = (t < NE) ? ei[NE + t] : (t - NE);
    atomicAdd(&deg[d], 1);
}

__global__ __launch_bounds__(256) void block_sums(const int* __restrict__ deg,
                                                  int* __restrict__ bsum) {
    int i = blockIdx.x * 256 + threadIdx.x;
    int d = (i < NN) ? deg[i] : 0;
#pragma unroll
    for (int off = 32; off > 0; off >>= 1) d += __shfl_down(d, off, 64);
    __shared__ int ws[4];
    if ((threadIdx.x & 63) == 0) ws[threadIdx.x >> 6] = d;
    __syncthreads();
    if (threadIdx.x == 0) bsum[blockIdx.x] = ws[0] + ws[1] + ws[2] + ws[3];
}

__global__ __launch_bounds__(512) void scan_bsum(const int* __restrict__ bsum,
                                                 int* __restrict__ bscan) {
    __shared__ int s[512];
    const int t = threadIdx.x;
    int v = (t < NBLK) ? bsum[t] : 0;
    s[t] = v;
    __syncthreads();
    for (int off = 1; off < 512; off <<= 1) {
        int u = (t >= off) ? s[t - off] : 0;
        __syncthreads();
        s[t] += u;
        __syncthreads();
    }
    if (t < NBLK) bscan[t] = s[t] - v;   // exclusive
}

__global__ __launch_bounds__(256) void scan_apply(const int* __restrict__ deg,
                                                  const int* __restrict__ bscan,
                                                  int* __restrict__ rowptr,
                                                  int* __restrict__ cursor,
                                                  float* __restrict__ dinv) {
    __shared__ int s[256];
    const int t = threadIdx.x;
    const int i = blockIdx.x * 256 + t;
    int d = (i < NN) ? deg[i] : 0;
    s[t] = d;
    __syncthreads();
    for (int off = 1; off < 256; off <<= 1) {
        int u = (t >= off) ? s[t - off] : 0;
        __syncthreads();
        s[t] += u;
        __syncthreads();
    }
    int excl = s[t] - d + bscan[blockIdx.x];
    if (i < NN) {
        rowptr[i] = excl;
        cursor[i] = excl;
        dinv[i] = rsqrtf((float)d);
        if (i == NN - 1) rowptr[NN] = excl + d;
    }
}

__global__ void fill_csr(const int* __restrict__ ei, int* __restrict__ cursor,
                         const float* __restrict__ dinv, int2* __restrict__ cw) {
    int t = blockIdx.x * blockDim.x + threadIdx.x;
    if (t >= TT) return;
    int s, d;
    if (t < NE) { s = ei[t]; d = ei[NE + t]; }
    else        { s = d = t - NE; }
    int pos = atomicAdd(&cursor[d], 1);
    cw[pos] = make_int2(s, __float_as_int(dinv[s]));
}

// ---------------- GEMM: Yh[N x F] (fp16) = X[N x 128] @ W[128 x F] ----------------
// 128 x F block tile, K chunks of 32, fp32 accumulate, fp16 store.

template <int F>
__global__ __launch_bounds__(256) void gemm_tile(const float* __restrict__ X,
                                                 const float* __restrict__ W,
                                                 __half* __restrict__ Yh) {
    constexpr int TN = (F == 128) ? 8 : 4;
    constexpr int WPAD = F + 4;
    __shared__ float Xl[32][132];
    __shared__ float Wl[32][WPAD];

    const int tid = threadIdx.x;
    const int wave = tid >> 6;
    const int lane = tid & 63;
    const int wrow = (wave & 1) * 64;
    const int wcol = (wave >> 1) * (F / 2);
    const int r0 = wrow + (lane & 7) * 8;
    const int c0 = wcol + (lane >> 3) * TN;
    const int grow0 = blockIdx.x * 128;

    float acc[8][TN];
#pragma unroll
    for (int i = 0; i < 8; i++)
#pragma unroll
        for (int j = 0; j < TN; j++) acc[i][j] = 0.f;

    const int kgX = tid & 7;
    const int rrX = tid >> 3;

    for (int kt = 0; kt < 128; kt += 32) {
#pragma unroll
        for (int p = 0; p < 4; p++) {
            int row = rrX + 32 * p;
            int gr = grow0 + row;
            float4 xv = make_float4(0.f, 0.f, 0.f, 0.f);
            if (gr < NN)
                xv = *reinterpret_cast<const float4*>(X + (size_t)gr * 128 + kt + kgX * 4);
            Xl[kgX * 4 + 0][row] = xv.x;
            Xl[kgX * 4 + 1][row] = xv.y;
            Xl[kgX * 4 + 2][row] = xv.z;
            Xl[kgX * 4 + 3][row] = xv.w;
        }
        {
            constexpr int GP = F / 4;
            int cg = tid % GP;
            int kr = tid / GP;
#pragma unroll
            for (int p = 0; p < (32 * GP) / 256; p++) {
                int k = kr + p * (256 / GP);
                float4 wv = *reinterpret_cast<const float4*>(W + (size_t)(kt + k) * F + cg * 4);
                *reinterpret_cast<float4*>(&Wl[k][cg * 4]) = wv;
            }
        }
        __syncthreads();
#pragma unroll
        for (int k = 0; k < 32; k++) {
            float a[8], b[TN];
            *reinterpret_cast<float4*>(&a[0]) = *reinterpret_cast<float4*>(&Xl[k][r0]);
            *reinterpret_cast<float4*>(&a[4]) = *reinterpret_cast<float4*>(&Xl[k][r0 + 4]);
            *reinterpret_cast<float4*>(&b[0]) = *reinterpret_cast<float4*>(&Wl[k][c0]);
            if constexpr (TN == 8)
                *reinterpret_cast<float4*>(&b[4]) = *reinterpret_cast<float4*>(&Wl[k][c0 + 4]);
#pragma unroll
            for (int i = 0; i < 8; i++)
#pragma unroll
                for (int j = 0; j < TN; j++) acc[i][j] += a[i] * b[j];
        }
        __syncthreads();
    }
#pragma unroll
    for (int i = 0; i < 8; i++) {
        int gr = grow0 + r0 + i;
        if (gr < NN) {
            __half hv[TN];
#pragma unroll
            for (int j = 0; j < TN; j++) hv[j] = __float2half_rn(acc[i][j]);
            __half* yp = Yh + (size_t)gr * F + c0;
            if constexpr (TN == 8)
                *reinterpret_cast<float4*>(yp) = *reinterpret_cast<float4*>(hv);
            else
                *reinterpret_cast<float2*>(yp) = *reinterpret_cast<float2*>(hv);
        }
    }
}

// ---------------- Aggregate: out[v] = dinv[v]*sum_e wgt[e]*XWh[col[e]] + b ----------------
// fp16 gather: F/8 lanes per node, one 16B (8-half) load per edge per lane.

template <int F, bool RELU>
__global__ __launch_bounds__(256) void aggregate_h(const __half* __restrict__ XWh,
                                                   const int* __restrict__ rowptr,
                                                   const int2* __restrict__ cw,
                                                   const float* __restrict__ dinv,
                                                   const float* __restrict__ bias,
                                                   float* __restrict__ out) {
    constexpr int TPN = F / 8;        // 16 (F=128) or 8 (F=64)
    constexpr int NPB = 256 / TPN;
    const int v = blockIdx.x * NPB + threadIdx.x / TPN;
    const int f = threadIdx.x % TPN;  // which 8-half chunk
    const int beg = rowptr[v];
    const int end = rowptr[v + 1];
    const float4* base = reinterpret_cast<const float4*>(XWh);  // row = TPN float4s
    float acc[8] = {0.f, 0.f, 0.f, 0.f, 0.f, 0.f, 0.f, 0.f};
#pragma unroll 4
    for (int e = beg; e < end; e++) {
        int2 c = cw[e];
        float w = __int_as_float(c.y);
        float4 raw = base[(size_t)c.x * TPN + f];
        const __half2* h2 = reinterpret_cast<const __half2*>(&raw);
#pragma unroll
        for (int q = 0; q < 4; q++) {
            float2 fv = __half22float2(h2[q]);
            acc[2 * q]     += w * fv.x;
            acc[2 * q + 1] += w * fv.y;
        }
    }
    const float dv = dinv[v];
    float r[8];
#pragma unroll
    for (int q = 0; q < 8; q++) {
        r[q] = dv * acc[q] + bias[f * 8 + q];
        if (RELU) r[q] = fmaxf(r[q], 0.f);
    }
    float* op = out + (size_t)v * F + f * 8;
    *reinterpret_cast<float4*>(op)     = make_float4(r[0], r[1], r[2], r[3]);
    *reinterpret_cast<float4*>(op + 4) = make_float4(r[4], r[5], r[6], r[7]);
}

// ---------------- launch ----------------

extern "C" void kernel_launch(void* const* d_in, const int* in_sizes, int n_in,
                              void* d_out, int out_size, void* d_ws, size_t ws_size,
                              hipStream_t stream) {
    const float* x  = (const float*)d_in[0];
    const int*   ei = (const int*)d_in[1];
    const float* W1 = (const float*)d_in[2];
    const float* b1 = (const float*)d_in[3];
    const float* W2 = (const float*)d_in[4];
    const float* b2 = (const float*)d_in[5];
    const float* W3 = (const float*)d_in[6];
    const float* b3 = (const float*)d_in[7];
    float* out = (float*)d_out;

    char* p = (char*)d_ws;
    int*    deg    = (int*)p;    p += 400000;
    int*    rowptr = (int*)p;    p += 400016;
    int*    cursor = (int*)p;    p += 400000;
    float*  dinv   = (float*)p;  p += 400000;
    int*    bsum   = (int*)p;    p += 1600;
    int*    bscan  = (int*)p;    p += 1600;
    int2*   cw     = (int2*)p;   p += (size_t)TT * 8;        // 13.6 MB
    __half* xwh    = (__half*)p; p += (size_t)NN * 128 * 2;  // 25.6 MB
    float*  h      = (float*)p;                               // 51.2 MB

    hipMemsetAsync(deg, 0, (size_t)NN * 4, stream);
    count_deg<<<(TT + 255) / 256, 256, 0, stream>>>(ei, deg);
    block_sums<<<NBLK, 256, 0, stream>>>(deg, bsum);
    scan_bsum<<<1, 512, 0, stream>>>(bsum, bscan);
    scan_apply<<<NBLK, 256, 0, stream>>>(deg, bscan, rowptr, cursor, dinv);
    fill_csr<<<(TT + 255) / 256, 256, 0, stream>>>(ei, cursor, dinv, cw);

    const int gb = (NN + 127) / 128;   // 782
    // layer 1
    gemm_tile<128><<<gb, 256, 0, stream>>>(x, W1, xwh);
    aggregate_h<128, true><<<NN / 16, 256, 0, stream>>>(xwh, rowptr, cw, dinv, b1, h);
    // layer 2
    gemm_tile<128><<<gb, 256, 0, stream>>>(h, W2, xwh);
    aggregate_h<128, true><<<NN / 16, 256, 0, stream>>>(xwh, rowptr, cw, dinv, b2, h);
    // layer 3 (no relu) -> d_out
    gemm_tile<64><<<gb, 256, 0, stream>>>(h, W3, xwh);
    aggregate_h<64, false><<<NN / 32, 256, 0, stream>>>(xwh, rowptr, cw, dinv, b3, out);
}

// Round 5
// 603.236 us; speedup vs baseline: 2.5252x; 1.0331x over previous
//
#include <hip/hip_runtime.h>
#include <hip/hip_fp16.h>

// GCN: 100K nodes, 1.6M edges, 128 -> 128 -> 128 -> 64 (fp32 in/out)
// CSR by dst via locality-staged counting sort -> per layer:
// tiled GEMM (fp32 acc, fp16 out) -> fused gather-aggregate (fp16 gather, fp32 acc).

#define NN 100000
#define NE 1600000
#define TT (NE + NN)              // edges + self loops
#define NBLK ((NN + 255) / 256)   // 391 scan blocks
#define BSH 9                      // bucket = dst >> 9 (512 nodes/bucket)
#define NBUCK ((NN + 511) / 512)   // 196
#define EPB1 16384                 // edges per pass-1 block
#define NPB1 ((TT + EPB1 - 1) / EPB1)   // 104

// ---------------- degree + scan ----------------

__global__ void count_deg(const int* __restrict__ ei, int* __restrict__ deg) {
    int t = blockIdx.x * blockDim.x + threadIdx.x;
    if (t >= TT) return;
    int d = (t < NE) ? ei[NE + t] : (t - NE);
    atomicAdd(&deg[d], 1);
}

__global__ __launch_bounds__(256) void block_sums(const int* __restrict__ deg,
                                                  int* __restrict__ bsum) {
    int i = blockIdx.x * 256 + threadIdx.x;
    int d = (i < NN) ? deg[i] : 0;
#pragma unroll
    for (int off = 32; off > 0; off >>= 1) d += __shfl_down(d, off, 64);
    __shared__ int ws[4];
    if ((threadIdx.x & 63) == 0) ws[threadIdx.x >> 6] = d;
    __syncthreads();
    if (threadIdx.x == 0) bsum[blockIdx.x] = ws[0] + ws[1] + ws[2] + ws[3];
}

__global__ __launch_bounds__(512) void scan_bsum(const int* __restrict__ bsum,
                                                 int* __restrict__ bscan) {
    __shared__ int s[512];
    const int t = threadIdx.x;
    int v = (t < NBLK) ? bsum[t] : 0;
    s[t] = v;
    __syncthreads();
    for (int off = 1; off < 512; off <<= 1) {
        int u = (t >= off) ? s[t - off] : 0;
        __syncthreads();
        s[t] += u;
        __syncthreads();
    }
    if (t < NBLK) bscan[t] = s[t] - v;   // exclusive
}

__global__ __launch_bounds__(256) void scan_apply(const int* __restrict__ deg,
                                                  const int* __restrict__ bscan,
                                                  int* __restrict__ rowptr,
                                                  int* __restrict__ gcursor,
                                                  float* __restrict__ dinv) {
    __shared__ int s[256];
    const int t = threadIdx.x;
    const int i = blockIdx.x * 256 + t;
    int d = (i < NN) ? deg[i] : 0;
    s[t] = d;
    __syncthreads();
    for (int off = 1; off < 256; off <<= 1) {
        int u = (t >= off) ? s[t - off] : 0;
        __syncthreads();
        s[t] += u;
        __syncthreads();
    }
    int excl = s[t] - d + bscan[blockIdx.x];
    if (i < NN) {
        rowptr[i] = excl;
        dinv[i] = rsqrtf((float)d);
        if ((i & 511) == 0) gcursor[i >> BSH] = excl;   // bucket base
        if (i == NN - 1) rowptr[NN] = excl + d;
    }
}

// ---------------- pass 1: partition edges into 196 dst-buckets ----------------
// LDS histogram -> one global atomic per (block,bucket) -> contiguous run writes.

__global__ __launch_bounds__(256) void partition_p1(const int* __restrict__ ei,
                                                    int* __restrict__ gcursor,
                                                    int2* __restrict__ part) {
    __shared__ int hist[NBUCK];
    const int tid = threadIdx.x;
    const int base = blockIdx.x * EPB1;
    for (int b = tid; b < NBUCK; b += 256) hist[b] = 0;
    __syncthreads();
    // phase A: count
    for (int i = tid; i < EPB1; i += 256) {
        int e = base + i;
        if (e >= TT) break;
        int d = (e < NE) ? ei[NE + e] : (e - NE);
        atomicAdd(&hist[d >> BSH], 1);
    }
    __syncthreads();
    // phase B: reserve; hist[b] becomes the running global cursor
    for (int b = tid; b < NBUCK; b += 256) {
        int cnt = hist[b];
        hist[b] = cnt ? atomicAdd(&gcursor[b], cnt) : 0;
    }
    __syncthreads();
    // phase C: place
    for (int i = tid; i < EPB1; i += 256) {
        int e = base + i;
        if (e >= TT) break;
        int s, d;
        if (e < NE) { s = ei[e]; d = ei[NE + e]; }
        else        { s = d = e - NE; }
        int pos = atomicAdd(&hist[d >> BSH], 1);
        part[pos] = make_int2(s, d);
    }
}

// ---------------- pass 2: within-bucket counting sort -> final CSR ----------------
// One block per bucket; LDS per-node cursors; all traffic bucket-local.

__global__ __launch_bounds__(256) void partition_p2(const int2* __restrict__ part,
                                                    const int* __restrict__ rowptr,
                                                    const float* __restrict__ dinv,
                                                    int2* __restrict__ cw) {
    __shared__ int cur[512];
    const int b = blockIdx.x;
    const int v0 = b << BSH;
    const int vend = min(v0 + 512, NN);
    const int tid = threadIdx.x;
    for (int j = tid; j < vend - v0; j += 256) cur[j] = rowptr[v0 + j];
    __syncthreads();
    const int beg = rowptr[v0];
    const int end = rowptr[vend];
    for (int i = beg + tid; i < end; i += 256) {
        int2 r = part[i];
        int pos = atomicAdd(&cur[r.y - v0], 1);
        cw[pos] = make_int2(r.x, __float_as_int(dinv[r.x]));
    }
}

// ---------------- GEMM: Yh[N x F] (fp16) = X[N x 128] @ W[128 x F] ----------------

template <int F>
__global__ __launch_bounds__(256) void gemm_tile(const float* __restrict__ X,
                                                 const float* __restrict__ W,
                                                 __half* __restrict__ Yh) {
    constexpr int TN = (F == 128) ? 8 : 4;
    constexpr int WPAD = F + 4;
    __shared__ float Xl[32][132];
    __shared__ float Wl[32][WPAD];

    const int tid = threadIdx.x;
    const int wave = tid >> 6;
    const int lane = tid & 63;
    const int wrow = (wave & 1) * 64;
    const int wcol = (wave >> 1) * (F / 2);
    const int r0 = wrow + (lane & 7) * 8;
    const int c0 = wcol + (lane >> 3) * TN;
    const int grow0 = blockIdx.x * 128;

    float acc[8][TN];
#pragma unroll
    for (int i = 0; i < 8; i++)
#pragma unroll
        for (int j = 0; j < TN; j++) acc[i][j] = 0.f;

    const int kgX = tid & 7;
    const int rrX = tid >> 3;

    for (int kt = 0; kt < 128; kt += 32) {
#pragma unroll
        for (int p = 0; p < 4; p++) {
            int row = rrX + 32 * p;
            int gr = grow0 + row;
            float4 xv = make_float4(0.f, 0.f, 0.f, 0.f);
            if (gr < NN)
                xv = *reinterpret_cast<const float4*>(X + (size_t)gr * 128 + kt + kgX * 4);
            Xl[kgX * 4 + 0][row] = xv.x;
            Xl[kgX * 4 + 1][row] = xv.y;
            Xl[kgX * 4 + 2][row] = xv.z;
            Xl[kgX * 4 + 3][row] = xv.w;
        }
        {
            constexpr int GP = F / 4;
            int cg = tid % GP;
            int kr = tid / GP;
#pragma unroll
            for (int p = 0; p < (32 * GP) / 256; p++) {
                int k = kr + p * (256 / GP);
                float4 wv = *reinterpret_cast<const float4*>(W + (size_t)(kt + k) * F + cg * 4);
                *reinterpret_cast<float4*>(&Wl[k][cg * 4]) = wv;
            }
        }
        __syncthreads();
#pragma unroll
        for (int k = 0; k < 32; k++) {
            float a[8], bb[TN];
            *reinterpret_cast<float4*>(&a[0]) = *reinterpret_cast<float4*>(&Xl[k][r0]);
            *reinterpret_cast<float4*>(&a[4]) = *reinterpret_cast<float4*>(&Xl[k][r0 + 4]);
            *reinterpret_cast<float4*>(&bb[0]) = *reinterpret_cast<float4*>(&Wl[k][c0]);
            if constexpr (TN == 8)
                *reinterpret_cast<float4*>(&bb[4]) = *reinterpret_cast<float4*>(&Wl[k][c0 + 4]);
#pragma unroll
            for (int i = 0; i < 8; i++)
#pragma unroll
                for (int j = 0; j < TN; j++) acc[i][j] += a[i] * bb[j];
        }
        __syncthreads();
    }
#pragma unroll
    for (int i = 0; i < 8; i++) {
        int gr = grow0 + r0 + i;
        if (gr < NN) {
            __half hv[TN];
#pragma unroll
            for (int j = 0; j < TN; j++) hv[j] = __float2half_rn(acc[i][j]);
            __half* yp = Yh + (size_t)gr * F + c0;
            if constexpr (TN == 8)
                *reinterpret_cast<float4*>(yp) = *reinterpret_cast<float4*>(hv);
            else
                *reinterpret_cast<float2*>(yp) = *reinterpret_cast<float2*>(hv);
        }
    }
}

// ---------------- Aggregate: out[v] = dinv[v]*sum_e wgt[e]*XWh[col[e]] + b ----------------

template <int F, bool RELU>
__global__ __launch_bounds__(256) void aggregate_h(const __half* __restrict__ XWh,
                                                   const int* __restrict__ rowptr,
                                                   const int2* __restrict__ cw,
                                                   const float* __restrict__ dinv,
                                                   const float* __restrict__ bias,
                                                   float* __restrict__ out) {
    constexpr int TPN = F / 8;
    constexpr int NPB = 256 / TPN;
    const int v = blockIdx.x * NPB + threadIdx.x / TPN;
    const int f = threadIdx.x % TPN;
    const int beg = rowptr[v];
    const int end = rowptr[v + 1];
    const float4* base = reinterpret_cast<const float4*>(XWh);
    float acc[8] = {0.f, 0.f, 0.f, 0.f, 0.f, 0.f, 0.f, 0.f};
#pragma unroll 4
    for (int e = beg; e < end; e++) {
        int2 c = cw[e];
        float w = __int_as_float(c.y);
        float4 raw = base[(size_t)c.x * TPN + f];
        const __half2* h2 = reinterpret_cast<const __half2*>(&raw);
#pragma unroll
        for (int q = 0; q < 4; q++) {
            float2 fv = __half22float2(h2[q]);
            acc[2 * q]     += w * fv.x;
            acc[2 * q + 1] += w * fv.y;
        }
    }
    const float dv = dinv[v];
    float r[8];
#pragma unroll
    for (int q = 0; q < 8; q++) {
        r[q] = dv * acc[q] + bias[f * 8 + q];
        if (RELU) r[q] = fmaxf(r[q], 0.f);
    }
    float* op = out + (size_t)v * F + f * 8;
    *reinterpret_cast<float4*>(op)     = make_float4(r[0], r[1], r[2], r[3]);
    *reinterpret_cast<float4*>(op + 4) = make_float4(r[4], r[5], r[6], r[7]);
}

// ---------------- launch ----------------

extern "C" void kernel_launch(void* const* d_in, const int* in_sizes, int n_in,
                              void* d_out, int out_size, void* d_ws, size_t ws_size,
                              hipStream_t stream) {
    const float* x  = (const float*)d_in[0];
    const int*   ei = (const int*)d_in[1];
    const float* W1 = (const float*)d_in[2];
    const float* b1 = (const float*)d_in[3];
    const float* W2 = (const float*)d_in[4];
    const float* b2 = (const float*)d_in[5];
    const float* W3 = (const float*)d_in[6];
    const float* b3 = (const float*)d_in[7];
    float* out = (float*)d_out;

    char* p = (char*)d_ws;
    int*    deg     = (int*)p;    p += 400000;
    int*    rowptr  = (int*)p;    p += 400016;
    float*  dinv    = (float*)p;  p += 400000;
    int*    bsum    = (int*)p;    p += 1600;
    int*    bscan   = (int*)p;    p += 1600;
    int*    gcursor = (int*)p;    p += 1024;                 // NBUCK=196 padded
    int2*   part    = (int2*)p;   p += (size_t)TT * 8;       // 13.6 MB
    int2*   cw      = (int2*)p;   p += (size_t)TT * 8;       // 13.6 MB
    __half* xwh     = (__half*)p; p += (size_t)NN * 128 * 2; // 25.6 MB
    float*  h       = (float*)p;                              // 51.2 MB

    hipMemsetAsync(deg, 0, (size_t)NN * 4, stream);
    count_deg<<<(TT + 255) / 256, 256, 0, stream>>>(ei, deg);
    block_sums<<<NBLK, 256, 0, stream>>>(deg, bsum);
    scan_bsum<<<1, 512, 0, stream>>>(bsum, bscan);
    scan_apply<<<NBLK, 256, 0, stream>>>(deg, bscan, rowptr, gcursor, dinv);
    partition_p1<<<NPB1, 256, 0, stream>>>(ei, gcursor, part);
    partition_p2<<<NBUCK, 256, 0, stream>>>(part, rowptr, dinv, cw);

    const int gb = (NN + 127) / 128;   // 782
    // layer 1
    gemm_tile<128><<<gb, 256, 0, stream>>>(x, W1, xwh);
    aggregate_h<128, true><<<NN / 16, 256, 0, stream>>>(xwh, rowptr, cw, dinv, b1, h);
    // layer 2
    gemm_tile<128><<<gb, 256, 0, stream>>>(h, W2, xwh);
    aggregate_h<128, true><<<NN / 16, 256, 0, stream>>>(xwh, rowptr, cw, dinv, b2, h);
    // layer 3 (no relu) -> d_out
    gemm_tile<64><<<gb, 256, 0, stream>>>(h, W3, xwh);
    aggregate_h<64, false><<<NN / 32, 256, 0, stream>>>(xwh, rowptr, cw, dinv, b3, out);
}

// Round 7
// 542.306 us; speedup vs baseline: 2.8089x; 1.1124x over previous
//
#include <hip/hip_runtime.h>
#include <hip/hip_fp16.h>

// GCN: 100K nodes, 1.6M edges, 128 -> 128 -> 128 -> 64 (fp32 in/out)
// CSR by dst via locality-staged counting sort -> per layer:
// MFMA GEMM (f16 inputs, fp32 acc, fp16 out) -> fused gather-aggregate
// (fp16 gather, fp32 acc, fp16 h / fp32 final).

#define NN 100000
#define NE 1600000
#define TT (NE + NN)              // edges + self loops
#define NBLK ((NN + 255) / 256)   // 391 scan blocks
#define BSH 9                      // bucket = dst >> 9 (512 nodes/bucket)
#define NBUCK ((NN + 511) / 512)   // 196
#define EPB1 16384                 // edges per pass-1 block
#define NPB1 ((TT + EPB1 - 1) / EPB1)   // 104

typedef _Float16 f16x8 __attribute__((ext_vector_type(8)));
typedef float f32x4 __attribute__((ext_vector_type(4)));

// ---------------- degree + scan ----------------

__global__ void count_deg(const int* __restrict__ ei, int* __restrict__ deg) {
    int t = blockIdx.x * blockDim.x + threadIdx.x;
    if (t >= TT) return;
    int d = (t < NE) ? ei[NE + t] : (t - NE);
    atomicAdd(&deg[d], 1);
}

__global__ __launch_bounds__(256) void block_sums(const int* __restrict__ deg,
                                                  int* __restrict__ bsum) {
    int i = blockIdx.x * 256 + threadIdx.x;
    int d = (i < NN) ? deg[i] : 0;
#pragma unroll
    for (int off = 32; off > 0; off >>= 1) d += __shfl_down(d, off, 64);
    __shared__ int ws[4];
    if ((threadIdx.x & 63) == 0) ws[threadIdx.x >> 6] = d;
    __syncthreads();
    if (threadIdx.x == 0) bsum[blockIdx.x] = ws[0] + ws[1] + ws[2] + ws[3];
}

__global__ __launch_bounds__(512) void scan_bsum(const int* __restrict__ bsum,
                                                 int* __restrict__ bscan) {
    __shared__ int s[512];
    const int t = threadIdx.x;
    int v = (t < NBLK) ? bsum[t] : 0;
    s[t] = v;
    __syncthreads();
    for (int off = 1; off < 512; off <<= 1) {
        int u = (t >= off) ? s[t - off] : 0;
        __syncthreads();
        s[t] += u;
        __syncthreads();
    }
    if (t < NBLK) bscan[t] = s[t] - v;   // exclusive
}

__global__ __launch_bounds__(256) void scan_apply(const int* __restrict__ deg,
                                                  const int* __restrict__ bscan,
                                                  int* __restrict__ rowptr,
                                                  int* __restrict__ gcursor,
                                                  float* __restrict__ dinv) {
    __shared__ int s[256];
    const int t = threadIdx.x;
    const int i = blockIdx.x * 256 + t;
    int d = (i < NN) ? deg[i] : 0;
    s[t] = d;
    __syncthreads();
    for (int off = 1; off < 256; off <<= 1) {
        int u = (t >= off) ? s[t - off] : 0;
        __syncthreads();
        s[t] += u;
        __syncthreads();
    }
    int excl = s[t] - d + bscan[blockIdx.x];
    if (i < NN) {
        rowptr[i] = excl;
        dinv[i] = rsqrtf((float)d);
        if ((i & 511) == 0) gcursor[i >> BSH] = excl;   // bucket base
        if (i == NN - 1) rowptr[NN] = excl + d;
    }
}

// ---------------- pass 1: partition edges into 196 dst-buckets ----------------

__global__ __launch_bounds__(256) void partition_p1(const int* __restrict__ ei,
                                                    int* __restrict__ gcursor,
                                                    int2* __restrict__ part) {
    __shared__ int hist[NBUCK];
    const int tid = threadIdx.x;
    const int base = blockIdx.x * EPB1;
    for (int b = tid; b < NBUCK; b += 256) hist[b] = 0;
    __syncthreads();
    for (int i = tid; i < EPB1; i += 256) {
        int e = base + i;
        if (e >= TT) break;
        int d = (e < NE) ? ei[NE + e] : (e - NE);
        atomicAdd(&hist[d >> BSH], 1);
    }
    __syncthreads();
    for (int b = tid; b < NBUCK; b += 256) {
        int cnt = hist[b];
        hist[b] = cnt ? atomicAdd(&gcursor[b], cnt) : 0;
    }
    __syncthreads();
    for (int i = tid; i < EPB1; i += 256) {
        int e = base + i;
        if (e >= TT) break;
        int s, d;
        if (e < NE) { s = ei[e]; d = ei[NE + e]; }
        else        { s = d = e - NE; }
        int pos = atomicAdd(&hist[d >> BSH], 1);
        part[pos] = make_int2(s, d);
    }
}

// ---------------- pass 2: within-bucket counting sort -> final CSR ----------------

__global__ __launch_bounds__(256) void partition_p2(const int2* __restrict__ part,
                                                    const int* __restrict__ rowptr,
                                                    const float* __restrict__ dinv,
                                                    int2* __restrict__ cw) {
    __shared__ int cur[512];
    const int b = blockIdx.x;
    const int v0 = b << BSH;
    const int vend = min(v0 + 512, NN);
    const int tid = threadIdx.x;
    for (int j = tid; j < vend - v0; j += 256) cur[j] = rowptr[v0 + j];
    __syncthreads();
    const int beg = rowptr[v0];
    const int end = rowptr[vend];
    for (int i = beg + tid; i < end; i += 256) {
        int2 r = part[i];
        int pos = atomicAdd(&cur[r.y - v0], 1);
        cw[pos] = make_int2(r.x, __float_as_int(dinv[r.x]));
    }
}

// ---------------- MFMA GEMM: Yh[N x F](fp16) = A[N x 128] @ W[128 x F] ----------------
// v_mfma_f32_16x16x32_f16. A from global (fp32 or fp16), W transposed fp16 in LDS.
// 256 thr = 4 waves x 16 rows = 64 rows/block; each wave sweeps all F/16 n-tiles.
// Frag layouts (m89/m91/m120-verified): A[m=lane&15][k=quad*8+j];
// B[k=quad*8+j][n=lane&15] (from Wt[n][k]); D col=lane&15, row=quad*4+reg.

template <int F, bool AHALF>
__global__ __launch_bounds__(256) void gemm_mfma(const void* __restrict__ Ap,
                                                 const float* __restrict__ W,
                                                 __half* __restrict__ Yh) {
    constexpr int NT = F / 16;
    __shared__ _Float16 Wt[F][136];   // [n][k], stride 136 halves = 272B (16B-aligned)

    const int tid = threadIdx.x;
    // stage W transposed as fp16 (coalesced float4 global reads)
    for (int i = tid; i < 32 * F; i += 256) {     // 128*F/4 float4s
        int k = i / (F / 4);
        int n0 = (i % (F / 4)) * 4;
        float4 wv = *reinterpret_cast<const float4*>(W + (size_t)k * F + n0);
        Wt[n0 + 0][k] = (_Float16)wv.x;
        Wt[n0 + 1][k] = (_Float16)wv.y;
        Wt[n0 + 2][k] = (_Float16)wv.z;
        Wt[n0 + 3][k] = (_Float16)wv.w;
    }
    __syncthreads();

    const int wave = tid >> 6;
    const int lane = tid & 63;
    const int m = lane & 15;
    const int q = lane >> 4;
    const int row = blockIdx.x * 64 + wave * 16 + m;
    const bool rok = row < NN;

    f32x4 acc[NT];
#pragma unroll
    for (int t = 0; t < NT; t++) acc[t] = (f32x4){0.f, 0.f, 0.f, 0.f};

#pragma unroll
    for (int kt = 0; kt < 128; kt += 32) {
        const int k0 = kt + q * 8;
        union { f16x8 v; _Float16 e[8]; } au;
        if (rok) {
            if constexpr (AHALF) {
                au.v = *reinterpret_cast<const f16x8*>(
                    (const __half*)Ap + (size_t)row * 128 + k0);
            } else {
                const float* A = (const float*)Ap;
                float4 x0 = *reinterpret_cast<const float4*>(A + (size_t)row * 128 + k0);
                float4 x1 = *reinterpret_cast<const float4*>(A + (size_t)row * 128 + k0 + 4);
                au.e[0] = (_Float16)x0.x; au.e[1] = (_Float16)x0.y;
                au.e[2] = (_Float16)x0.z; au.e[3] = (_Float16)x0.w;
                au.e[4] = (_Float16)x1.x; au.e[5] = (_Float16)x1.y;
                au.e[6] = (_Float16)x1.z; au.e[7] = (_Float16)x1.w;
            }
        } else {
#pragma unroll
            for (int j = 0; j < 8; j++) au.e[j] = (_Float16)0.f;
        }
#pragma unroll
        for (int t = 0; t < NT; t++) {
            // FIX (R6 bug): B k-slice must include the kt tile offset.
            f16x8 bf = *reinterpret_cast<const f16x8*>(&Wt[t * 16 + m][kt + q * 8]);
            acc[t] = __builtin_amdgcn_mfma_f32_16x16x32_f16(au.v, bf, acc[t], 0, 0, 0);
        }
    }
    // epilogue: D row = q*4+reg, col = t*16+m
#pragma unroll
    for (int r = 0; r < 4; r++) {
        int grow = blockIdx.x * 64 + wave * 16 + q * 4 + r;
        if (grow < NN) {
            __half* yp = Yh + (size_t)grow * F + m;
#pragma unroll
            for (int t = 0; t < NT; t++)
                yp[t * 16] = __float2half_rn(acc[t][r]);
        }
    }
}

// ---------------- Aggregate: out[v] = dinv[v]*sum_e wgt[e]*XWh[col[e]] + b ----------------

template <int F, bool RELU, typename OT>
__global__ __launch_bounds__(256) void aggregate_h(const __half* __restrict__ XWh,
                                                   const int* __restrict__ rowptr,
                                                   const int2* __restrict__ cw,
                                                   const float* __restrict__ dinv,
                                                   const float* __restrict__ bias,
                                                   OT* __restrict__ out) {
    constexpr int TPN = F / 8;
    constexpr int NPB = 256 / TPN;
    const int v = blockIdx.x * NPB + threadIdx.x / TPN;
    const int f = threadIdx.x % TPN;
    const int beg = rowptr[v];
    const int end = rowptr[v + 1];
    const float4* base = reinterpret_cast<const float4*>(XWh);
    float acc[8] = {0.f, 0.f, 0.f, 0.f, 0.f, 0.f, 0.f, 0.f};
#pragma unroll 4
    for (int e = beg; e < end; e++) {
        int2 c = cw[e];
        float w = __int_as_float(c.y);
        float4 raw = base[(size_t)c.x * TPN + f];
        const __half2* h2 = reinterpret_cast<const __half2*>(&raw);
#pragma unroll
        for (int q = 0; q < 4; q++) {
            float2 fv = __half22float2(h2[q]);
            acc[2 * q]     += w * fv.x;
            acc[2 * q + 1] += w * fv.y;
        }
    }
    const float dv = dinv[v];
    float r[8];
#pragma unroll
    for (int q = 0; q < 8; q++) {
        r[q] = dv * acc[q] + bias[f * 8 + q];
        if (RELU) r[q] = fmaxf(r[q], 0.f);
    }
    if constexpr (sizeof(OT) == 2) {
        union { f16x8 v; _Float16 e[8]; } hu;
#pragma unroll
        for (int q = 0; q < 8; q++) hu.e[q] = (_Float16)r[q];
        *reinterpret_cast<f16x8*>((__half*)out + (size_t)v * F + f * 8) = hu.v;
    } else {
        float* op = (float*)out + (size_t)v * F + f * 8;
        *reinterpret_cast<float4*>(op)     = make_float4(r[0], r[1], r[2], r[3]);
        *reinterpret_cast<float4*>(op + 4) = make_float4(r[4], r[5], r[6], r[7]);
    }
}

// ---------------- launch ----------------

extern "C" void kernel_launch(void* const* d_in, const int* in_sizes, int n_in,
                              void* d_out, int out_size, void* d_ws, size_t ws_size,
                              hipStream_t stream) {
    const float* x  = (const float*)d_in[0];
    const int*   ei = (const int*)d_in[1];
    const float* W1 = (const float*)d_in[2];
    const float* b1 = (const float*)d_in[3];
    const float* W2 = (const float*)d_in[4];
    const float* b2 = (const float*)d_in[5];
    const float* W3 = (const float*)d_in[6];
    const float* b3 = (const float*)d_in[7];
    float* out = (float*)d_out;

    char* p = (char*)d_ws;
    int*    deg     = (int*)p;    p += 400000;
    int*    rowptr  = (int*)p;    p += 400016;
    float*  dinv    = (float*)p;  p += 400000;
    int*    bsum    = (int*)p;    p += 1600;
    int*    bscan   = (int*)p;    p += 1600;
    int*    gcursor = (int*)p;    p += 1024;                 // NBUCK=196 padded
    int2*   part    = (int2*)p;   p += (size_t)TT * 8;       // 13.6 MB
    int2*   cw      = (int2*)p;   p += (size_t)TT * 8;       // 13.6 MB
    __half* xwh     = (__half*)p; p += (size_t)NN * 128 * 2; // 25.6 MB
    __half* h       = (__half*)p;                             // 25.6 MB

    hipMemsetAsync(deg, 0, (size_t)NN * 4, stream);
    count_deg<<<(TT + 255) / 256, 256, 0, stream>>>(ei, deg);
    block_sums<<<NBLK, 256, 0, stream>>>(deg, bsum);
    scan_bsum<<<1, 512, 0, stream>>>(bsum, bscan);
    scan_apply<<<NBLK, 256, 0, stream>>>(deg, bscan, rowptr, gcursor, dinv);
    partition_p1<<<NPB1, 256, 0, stream>>>(ei, gcursor, part);
    partition_p2<<<NBUCK, 256, 0, stream>>>(part, rowptr, dinv, cw);

    const int gb = (NN + 63) / 64;   // 1563
    // layer 1 (A fp32)
    gemm_mfma<128, false><<<gb, 256, 0, stream>>>(x, W1, xwh);
    aggregate_h<128, true, __half><<<NN / 16, 256, 0, stream>>>(
        xwh, rowptr, cw, dinv, b1, h);
    // layer 2 (A fp16)
    gemm_mfma<128, true><<<gb, 256, 0, stream>>>(h, W2, xwh);
    aggregate_h<128, true, __half><<<NN / 16, 256, 0, stream>>>(
        xwh, rowptr, cw, dinv, b2, h);
    // layer 3 (A fp16, no relu, fp32 out) -> d_out
    gemm_mfma<64, true><<<gb, 256, 0, stream>>>(h, W3, xwh);
    aggregate_h<64, false, float><<<NN / 32, 256, 0, stream>>>(
        xwh, rowptr, cw, dinv, b3, out);
}

// Round 8
// 541.560 us; speedup vs baseline: 2.8128x; 1.0014x over previous
//
#include <hip/hip_runtime.h>
#include <hip/hip_fp16.h>

// GCN: 100K nodes, 1.6M edges, 128 -> 128 -> 128 -> 64 (fp32 in/out)
// CSR by dst via locality-staged counting sort (packed 4B records) ->
// per layer: MFMA GEMM (fp32 acc, fp16 out pre-scaled by dinv[row], coalesced
// LDS epilogue) -> gather-aggregate (weightless: sum of pre-scaled rows).

#define NN 100000
#define NE 1600000
#define TT (NE + NN)              // edges + self loops
#define NBLK ((NN + 255) / 256)   // 391 scan blocks
#define BSH 9                      // bucket = dst >> 9 (512 nodes/bucket)
#define NBUCK ((NN + 511) / 512)   // 196
#define EPB1 16384                 // edges per pass-1 block
#define NPB1 ((TT + EPB1 - 1) / EPB1)   // 104

typedef _Float16 f16x8 __attribute__((ext_vector_type(8)));
typedef float f32x4 __attribute__((ext_vector_type(4)));

// ---------------- degree + scan ----------------

__global__ void count_deg(const int* __restrict__ ei, int* __restrict__ deg) {
    int t = blockIdx.x * blockDim.x + threadIdx.x;
    if (t >= TT) return;
    int d = (t < NE) ? ei[NE + t] : (t - NE);
    atomicAdd(&deg[d], 1);
}

__global__ __launch_bounds__(256) void block_sums(const int* __restrict__ deg,
                                                  int* __restrict__ bsum) {
    int i = blockIdx.x * 256 + threadIdx.x;
    int d = (i < NN) ? deg[i] : 0;
#pragma unroll
    for (int off = 32; off > 0; off >>= 1) d += __shfl_down(d, off, 64);
    __shared__ int ws[4];
    if ((threadIdx.x & 63) == 0) ws[threadIdx.x >> 6] = d;
    __syncthreads();
    if (threadIdx.x == 0) bsum[blockIdx.x] = ws[0] + ws[1] + ws[2] + ws[3];
}

__global__ __launch_bounds__(512) void scan_bsum(const int* __restrict__ bsum,
                                                 int* __restrict__ bscan) {
    __shared__ int s[512];
    const int t = threadIdx.x;
    int v = (t < NBLK) ? bsum[t] : 0;
    s[t] = v;
    __syncthreads();
    for (int off = 1; off < 512; off <<= 1) {
        int u = (t >= off) ? s[t - off] : 0;
        __syncthreads();
        s[t] += u;
        __syncthreads();
    }
    if (t < NBLK) bscan[t] = s[t] - v;   // exclusive
}

__global__ __launch_bounds__(256) void scan_apply(const int* __restrict__ deg,
                                                  const int* __restrict__ bscan,
                                                  int* __restrict__ rowptr,
                                                  int* __restrict__ gcursor,
                                                  float* __restrict__ dinv) {
    __shared__ int s[256];
    const int t = threadIdx.x;
    const int i = blockIdx.x * 256 + t;
    int d = (i < NN) ? deg[i] : 0;
    s[t] = d;
    __syncthreads();
    for (int off = 1; off < 256; off <<= 1) {
        int u = (t >= off) ? s[t - off] : 0;
        __syncthreads();
        s[t] += u;
        __syncthreads();
    }
    int excl = s[t] - d + bscan[blockIdx.x];
    if (i < NN) {
        rowptr[i] = excl;
        dinv[i] = rsqrtf((float)d);
        if ((i & 511) == 0) gcursor[i >> BSH] = excl;   // bucket base
        if (i == NN - 1) rowptr[NN] = excl + d;
    }
}

// ---------------- pass 1: partition into 196 dst-buckets, packed 4B records ----
// record = src | (dst & 511) << 17   (src < 2^17, local dst < 2^9)

__global__ __launch_bounds__(256) void partition_p1(const int* __restrict__ ei,
                                                    int* __restrict__ gcursor,
                                                    int* __restrict__ part) {
    __shared__ int hist[NBUCK];
    const int tid = threadIdx.x;
    const int base = blockIdx.x * EPB1;
    for (int b = tid; b < NBUCK; b += 256) hist[b] = 0;
    __syncthreads();
    for (int i = tid; i < EPB1; i += 256) {
        int e = base + i;
        if (e >= TT) break;
        int d = (e < NE) ? ei[NE + e] : (e - NE);
        atomicAdd(&hist[d >> BSH], 1);
    }
    __syncthreads();
    for (int b = tid; b < NBUCK; b += 256) {
        int cnt = hist[b];
        hist[b] = cnt ? atomicAdd(&gcursor[b], cnt) : 0;
    }
    __syncthreads();
    for (int i = tid; i < EPB1; i += 256) {
        int e = base + i;
        if (e >= TT) break;
        int s, d;
        if (e < NE) { s = ei[e]; d = ei[NE + e]; }
        else        { s = d = e - NE; }
        int pos = atomicAdd(&hist[d >> BSH], 1);
        part[pos] = s | ((d & 511) << 17);
    }
}

// ---------------- pass 2: within-bucket counting sort -> col[] ----------------

__global__ __launch_bounds__(256) void partition_p2(const int* __restrict__ part,
                                                    const int* __restrict__ rowptr,
                                                    int* __restrict__ col) {
    __shared__ int cur[512];
    const int b = blockIdx.x;
    const int v0 = b << BSH;
    const int vend = min(v0 + 512, NN);
    const int tid = threadIdx.x;
    for (int j = tid; j < vend - v0; j += 256) cur[j] = rowptr[v0 + j];
    __syncthreads();
    const int beg = rowptr[v0];
    const int end = rowptr[vend];
    for (int i = beg + tid; i < end; i += 256) {
        int r = part[i];
        int src = r & 0x1FFFF;
        int ld = ((unsigned)r) >> 17;
        int pos = atomicAdd(&cur[ld], 1);
        col[pos] = src;
    }
}

// ---------------- MFMA GEMM: Yh[N x F](fp16) = dinv[row] * (A[N x 128] @ W) ----
// v_mfma_f32_16x16x32_f16. W transposed fp16 in LDS; D-tile staged through LDS
// for coalesced f16x8 stores. Frag layouts (m89/m91/m120-verified):
// A[m=lane&15][k=quad*8+j]; B[k][n] from Wt[n][k]; D col=lane&15, row=quad*4+reg.

template <int F, bool AHALF>
__global__ __launch_bounds__(256) void gemm_mfma(const void* __restrict__ Ap,
                                                 const float* __restrict__ W,
                                                 const float* __restrict__ dinv,
                                                 __half* __restrict__ Yh) {
    constexpr int NT = F / 16;
    __shared__ _Float16 Wt[F][136];   // [n][k], 272B row stride (16B-aligned)
    __shared__ _Float16 Yl[64][136];  // D staging

    const int tid = threadIdx.x;
    for (int i = tid; i < 32 * F; i += 256) {     // 128*F/4 float4s
        int k = i / (F / 4);
        int n0 = (i % (F / 4)) * 4;
        float4 wv = *reinterpret_cast<const float4*>(W + (size_t)k * F + n0);
        Wt[n0 + 0][k] = (_Float16)wv.x;
        Wt[n0 + 1][k] = (_Float16)wv.y;
        Wt[n0 + 2][k] = (_Float16)wv.z;
        Wt[n0 + 3][k] = (_Float16)wv.w;
    }
    __syncthreads();

    const int wave = tid >> 6;
    const int lane = tid & 63;
    const int m = lane & 15;
    const int q = lane >> 4;
    const int grow0 = blockIdx.x * 64;
    const int row = grow0 + wave * 16 + m;
    const bool rok = row < NN;

    f32x4 acc[NT];
#pragma unroll
    for (int t = 0; t < NT; t++) acc[t] = (f32x4){0.f, 0.f, 0.f, 0.f};

#pragma unroll
    for (int kt = 0; kt < 128; kt += 32) {
        const int k0 = kt + q * 8;
        union { f16x8 v; _Float16 e[8]; } au;
        if (rok) {
            if constexpr (AHALF) {
                au.v = *reinterpret_cast<const f16x8*>(
                    (const __half*)Ap + (size_t)row * 128 + k0);
            } else {
                const float* A = (const float*)Ap;
                float4 x0 = *reinterpret_cast<const float4*>(A + (size_t)row * 128 + k0);
                float4 x1 = *reinterpret_cast<const float4*>(A + (size_t)row * 128 + k0 + 4);
                au.e[0] = (_Float16)x0.x; au.e[1] = (_Float16)x0.y;
                au.e[2] = (_Float16)x0.z; au.e[3] = (_Float16)x0.w;
                au.e[4] = (_Float16)x1.x; au.e[5] = (_Float16)x1.y;
                au.e[6] = (_Float16)x1.z; au.e[7] = (_Float16)x1.w;
            }
        } else {
#pragma unroll
            for (int j = 0; j < 8; j++) au.e[j] = (_Float16)0.f;
        }
#pragma unroll
        for (int t = 0; t < NT; t++) {
            f16x8 bf = *reinterpret_cast<const f16x8*>(&Wt[t * 16 + m][kt + q * 8]);
            acc[t] = __builtin_amdgcn_mfma_f32_16x16x32_f16(au.v, bf, acc[t], 0, 0, 0);
        }
    }
    // epilogue: scale by dinv[row], stage in LDS, store coalesced
#pragma unroll
    for (int r = 0; r < 4; r++) {
        int lrow = wave * 16 + q * 4 + r;
        int gr = grow0 + lrow;
        float s = (gr < NN) ? dinv[gr] : 0.f;
#pragma unroll
        for (int t = 0; t < NT; t++)
            Yl[lrow][t * 16 + m] = (_Float16)(s * acc[t][r]);
    }
    __syncthreads();
    constexpr int CH = F / 8;   // f16x8 chunks per row
    for (int i = tid; i < 64 * CH; i += 256) {
        int lrow = i / CH, c = i % CH;
        int gr = grow0 + lrow;
        if (gr < NN)
            *reinterpret_cast<f16x8*>(Yh + (size_t)gr * F + c * 8) =
                *reinterpret_cast<const f16x8*>(&Yl[lrow][c * 8]);
    }
}

// -------- Aggregate: out[v] = dinv[v]*sum_e XWh[col[e]] + b  (rows pre-scaled) ----

template <int F, bool RELU, typename OT>
__global__ __launch_bounds__(256) void aggregate_h(const __half* __restrict__ XWh,
                                                   const int* __restrict__ rowptr,
                                                   const int* __restrict__ col,
                                                   const float* __restrict__ dinv,
                                                   const float* __restrict__ bias,
                                                   OT* __restrict__ out) {
    constexpr int TPN = F / 8;
    constexpr int NPB = 256 / TPN;
    const int v = blockIdx.x * NPB + threadIdx.x / TPN;
    const int f = threadIdx.x % TPN;
    const int beg = rowptr[v];
    const int end = rowptr[v + 1];
    const float4* base = reinterpret_cast<const float4*>(XWh);
    float acc[8] = {0.f, 0.f, 0.f, 0.f, 0.f, 0.f, 0.f, 0.f};
#pragma unroll 4
    for (int e = beg; e < end; e++) {
        int u = col[e];
        float4 raw = base[(size_t)u * TPN + f];
        const __half2* h2 = reinterpret_cast<const __half2*>(&raw);
#pragma unroll
        for (int q = 0; q < 4; q++) {
            float2 fv = __half22float2(h2[q]);
            acc[2 * q]     += fv.x;
            acc[2 * q + 1] += fv.y;
        }
    }
    const float dv = dinv[v];
    float r[8];
#pragma unroll
    for (int q = 0; q < 8; q++) {
        r[q] = dv * acc[q] + bias[f * 8 + q];
        if (RELU) r[q] = fmaxf(r[q], 0.f);
    }
    if constexpr (sizeof(OT) == 2) {
        union { f16x8 v; _Float16 e[8]; } hu;
#pragma unroll
        for (int q = 0; q < 8; q++) hu.e[q] = (_Float16)r[q];
        *reinterpret_cast<f16x8*>((__half*)out + (size_t)v * F + f * 8) = hu.v;
    } else {
        float* op = (float*)out + (size_t)v * F + f * 8;
        *reinterpret_cast<float4*>(op)     = make_float4(r[0], r[1], r[2], r[3]);
        *reinterpret_cast<float4*>(op + 4) = make_float4(r[4], r[5], r[6], r[7]);
    }
}

// ---------------- launch ----------------

extern "C" void kernel_launch(void* const* d_in, const int* in_sizes, int n_in,
                              void* d_out, int out_size, void* d_ws, size_t ws_size,
                              hipStream_t stream) {
    const float* x  = (const float*)d_in[0];
    const int*   ei = (const int*)d_in[1];
    const float* W1 = (const float*)d_in[2];
    const float* b1 = (const float*)d_in[3];
    const float* W2 = (const float*)d_in[4];
    const float* b2 = (const float*)d_in[5];
    const float* W3 = (const float*)d_in[6];
    const float* b3 = (const float*)d_in[7];
    float* out = (float*)d_out;

    char* p = (char*)d_ws;
    int*    deg     = (int*)p;    p += 400000;
    int*    rowptr  = (int*)p;    p += 400016;
    float*  dinv    = (float*)p;  p += 400000;
    int*    bsum    = (int*)p;    p += 1600;
    int*    bscan   = (int*)p;    p += 1600;
    int*    gcursor = (int*)p;    p += 1024;                 // NBUCK=196 padded
    int*    part    = (int*)p;    p += (size_t)TT * 4;       // 6.8 MB
    int*    col     = (int*)p;    p += (size_t)TT * 4;       // 6.8 MB
    __half* xwh     = (__half*)p; p += (size_t)NN * 128 * 2; // 25.6 MB
    __half* h       = (__half*)p;                             // 25.6 MB

    hipMemsetAsync(deg, 0, (size_t)NN * 4, stream);
    count_deg<<<(TT + 255) / 256, 256, 0, stream>>>(ei, deg);
    block_sums<<<NBLK, 256, 0, stream>>>(deg, bsum);
    scan_bsum<<<1, 512, 0, stream>>>(bsum, bscan);
    scan_apply<<<NBLK, 256, 0, stream>>>(deg, bscan, rowptr, gcursor, dinv);
    partition_p1<<<NPB1, 256, 0, stream>>>(ei, gcursor, part);
    partition_p2<<<NBUCK, 256, 0, stream>>>(part, rowptr, col);

    const int gb = (NN + 63) / 64;   // 1563
    // layer 1 (A fp32)
    gemm_mfma<128, false><<<gb, 256, 0, stream>>>(x, W1, dinv, xwh);
    aggregate_h<128, true, __half><<<NN / 16, 256, 0, stream>>>(
        xwh, rowptr, col, dinv, b1, h);
    // layer 2 (A fp16)
    gemm_mfma<128, true><<<gb, 256, 0, stream>>>(h, W2, dinv, xwh);
    aggregate_h<128, true, __half><<<NN / 16, 256, 0, stream>>>(
        xwh, rowptr, col, dinv, b2, h);
    // layer 3 (A fp16, no relu, fp32 out) -> d_out
    gemm_mfma<64, true><<<gb, 256, 0, stream>>>(h, W3, dinv, xwh);
    aggregate_h<64, false, float><<<NN / 32, 256, 0, stream>>>(
        xwh, rowptr, col, dinv, b3, out);
}

// Round 9
// 504.737 us; speedup vs baseline: 3.0180x; 1.0730x over previous
//
#include <hip/hip_runtime.h>
#include <hip/hip_fp16.h>

// GCN: 100K nodes, 1.6M edges, 128 -> 128 -> 128 -> 64 (fp32 in/out)
// CSR by dst via bucket partition (4B packed records); degrees/rowptr/dinv
// computed bucket-locally in p2 (no global random atomics anywhere).
// Per layer: MFMA GEMM (W pre-transposed fp16 in global, fp32 acc, out
// pre-scaled by dinv[row], coalesced LDS epilogue) -> gather-aggregate.

#define NN 100000
#define NE 1600000
#define TT (NE + NN)              // edges + self loops
#define BSH 9                      // bucket = dst >> 9 (512 nodes/bucket)
#define NBUCK ((NN + 511) / 512)   // 196
#define EPB1 16384                 // edges per partition block
#define NPB1 ((TT + EPB1 - 1) / EPB1)   // 104

typedef _Float16 f16x8 __attribute__((ext_vector_type(8)));
typedef float f32x4 __attribute__((ext_vector_type(4)));

// ---------------- bucket histogram (replaces count_deg's 1.7M atomics) -------

__global__ __launch_bounds__(256) void bucket_count(const int* __restrict__ ei,
                                                    int* __restrict__ gbc) {
    __shared__ int hist[NBUCK];
    const int tid = threadIdx.x;
    const int base = blockIdx.x * EPB1;
    for (int b = tid; b < NBUCK; b += 256) hist[b] = 0;
    __syncthreads();
    for (int i = tid; i < EPB1; i += 256) {
        int e = base + i;
        if (e >= TT) break;
        int d = (e < NE) ? ei[NE + e] : (e - NE);
        atomicAdd(&hist[d >> BSH], 1);
    }
    __syncthreads();
    for (int b = tid; b < NBUCK; b += 256)
        if (hist[b]) atomicAdd(&gbc[b], hist[b]);
}

// single tiny block: exclusive scan of 196 bucket counts -> bbase, gcursor

__global__ __launch_bounds__(256) void scan_buckets(const int* __restrict__ gbc,
                                                    int* __restrict__ bbase,
                                                    int* __restrict__ gcursor,
                                                    int* __restrict__ rowptr) {
    __shared__ int s[256];
    const int t = threadIdx.x;
    int v = (t < NBUCK) ? gbc[t] : 0;
    s[t] = v;
    __syncthreads();
    for (int off = 1; off < 256; off <<= 1) {
        int u = (t >= off) ? s[t - off] : 0;
        __syncthreads();
        s[t] += u;
        __syncthreads();
    }
    if (t < NBUCK) {
        int excl = s[t] - v;
        bbase[t] = excl;
        gcursor[t] = excl;
    }
    if (t == 0) { bbase[NBUCK] = TT; rowptr[NN] = TT; }
}

// ---------------- pass 1: partition into 196 dst-buckets, packed 4B records ----
// record = src | (dst & 511) << 17   (src < 2^17, local dst < 2^9)

__global__ __launch_bounds__(256) void partition_p1(const int* __restrict__ ei,
                                                    int* __restrict__ gcursor,
                                                    int* __restrict__ part) {
    __shared__ int hist[NBUCK];
    const int tid = threadIdx.x;
    const int base = blockIdx.x * EPB1;
    for (int b = tid; b < NBUCK; b += 256) hist[b] = 0;
    __syncthreads();
    for (int i = tid; i < EPB1; i += 256) {
        int e = base + i;
        if (e >= TT) break;
        int d = (e < NE) ? ei[NE + e] : (e - NE);
        atomicAdd(&hist[d >> BSH], 1);
    }
    __syncthreads();
    for (int b = tid; b < NBUCK; b += 256) {
        int cnt = hist[b];
        hist[b] = cnt ? atomicAdd(&gcursor[b], cnt) : 0;
    }
    __syncthreads();
    for (int i = tid; i < EPB1; i += 256) {
        int e = base + i;
        if (e >= TT) break;
        int s, d;
        if (e < NE) { s = ei[e]; d = ei[NE + e]; }
        else        { s = d = e - NE; }
        int pos = atomicAdd(&hist[d >> BSH], 1);
        part[pos] = s | ((d & 511) << 17);
    }
}

// -------- pass 2: bucket-local count + scan + rowptr/dinv + counting sort ------

__global__ __launch_bounds__(256) void partition_p2(const int* __restrict__ part,
                                                    const int* __restrict__ bbase,
                                                    int* __restrict__ rowptr,
                                                    float* __restrict__ dinv,
                                                    int* __restrict__ col) {
    __shared__ int cnt[512];
    __shared__ int scn[512];
    __shared__ int cur[512];
    const int b = blockIdx.x;
    const int v0 = b << BSH;
    const int nv = min(512, NN - v0);
    const int tid = threadIdx.x;
    const int base = bbase[b];
    const int nrec = bbase[b + 1] - base;

    cnt[tid] = 0; cnt[tid + 256] = 0;
    __syncthreads();
    for (int i = tid; i < nrec; i += 256)
        atomicAdd(&cnt[((unsigned)part[base + i]) >> 17], 1);
    __syncthreads();
    scn[tid] = cnt[tid]; scn[tid + 256] = cnt[tid + 256];
    __syncthreads();
    // inclusive Hillis-Steele over 512 (2 elems/thread)
    for (int off = 1; off < 512; off <<= 1) {
        int a = (tid >= off) ? scn[tid - off] : 0;
        int c = (tid + 256 >= off) ? scn[tid + 256 - off] : 0;
        __syncthreads();
        scn[tid] += a; scn[tid + 256] += c;
        __syncthreads();
    }
#pragma unroll
    for (int p = 0; p < 2; p++) {
        int j = tid + p * 256;
        if (j < nv) {
            int excl = scn[j] - cnt[j];
            rowptr[v0 + j] = base + excl;
            dinv[v0 + j] = rsqrtf((float)cnt[j]);   // deg >= 1 (self loop)
            cur[j] = base + excl;
        }
    }
    __syncthreads();
    for (int i = tid; i < nrec; i += 256) {
        int r = part[base + i];
        int pos = atomicAdd(&cur[((unsigned)r) >> 17], 1);
        col[pos] = r & 0x1FFFF;
    }
}

// ---------------- W pre-transpose: W[128][F] fp32 -> Wt[F][128] fp16 ----------

__global__ __launch_bounds__(256) void wt_conv_all(const float* __restrict__ W1,
                                                   const float* __restrict__ W2,
                                                   const float* __restrict__ W3,
                                                   _Float16* __restrict__ Wt1,
                                                   _Float16* __restrict__ Wt2,
                                                   _Float16* __restrict__ Wt3) {
    int idx = blockIdx.x * 256 + threadIdx.x;
    if (idx < 16384) {
        Wt1[(idx % 128) * 128 + idx / 128] = (_Float16)W1[idx];
    } else if (idx < 32768) {
        int i = idx - 16384;
        Wt2[(i % 128) * 128 + i / 128] = (_Float16)W2[i];
    } else if (idx < 40960) {
        int i = idx - 32768;
        Wt3[(i % 64) * 128 + i / 64] = (_Float16)W3[i];
    }
}

// ---------------- MFMA GEMM: Yh[N x F](fp16) = dinv[row] * (A[N x 128] @ W) ----
// v_mfma_f32_16x16x32_f16; B-fragments straight from global Wt (L1/L2-hot,
// 32 KB). D staged through LDS for coalesced f16x8 stores.
// Frag layouts (m89/m91/m120-verified): A[m=lane&15][k=quad*8+j];
// B[k][n] from Wt[n][k]; D col=lane&15, row=quad*4+reg.

template <int F, bool AHALF>
__global__ __launch_bounds__(256) void gemm_mfma(const void* __restrict__ Ap,
                                                 const _Float16* __restrict__ Wt,
                                                 const float* __restrict__ dinv,
                                                 __half* __restrict__ Yh) {
    constexpr int NT = F / 16;
    __shared__ _Float16 Yl[64][136];

    const int tid = threadIdx.x;
    const int wave = tid >> 6;
    const int lane = tid & 63;
    const int m = lane & 15;
    const int q = lane >> 4;
    const int grow0 = blockIdx.x * 64;
    const int row = grow0 + wave * 16 + m;
    const bool rok = row < NN;

    f32x4 acc[NT];
#pragma unroll
    for (int t = 0; t < NT; t++) acc[t] = (f32x4){0.f, 0.f, 0.f, 0.f};

#pragma unroll
    for (int kt = 0; kt < 128; kt += 32) {
        const int k0 = kt + q * 8;
        union { f16x8 v; _Float16 e[8]; } au;
        if (rok) {
            if constexpr (AHALF) {
                au.v = *reinterpret_cast<const f16x8*>(
                    (const __half*)Ap + (size_t)row * 128 + k0);
            } else {
                const float* A = (const float*)Ap;
                float4 x0 = *reinterpret_cast<const float4*>(A + (size_t)row * 128 + k0);
                float4 x1 = *reinterpret_cast<const float4*>(A + (size_t)row * 128 + k0 + 4);
                au.e[0] = (_Float16)x0.x; au.e[1] = (_Float16)x0.y;
                au.e[2] = (_Float16)x0.z; au.e[3] = (_Float16)x0.w;
                au.e[4] = (_Float16)x1.x; au.e[5] = (_Float16)x1.y;
                au.e[6] = (_Float16)x1.z; au.e[7] = (_Float16)x1.w;
            }
        } else {
#pragma unroll
            for (int j = 0; j < 8; j++) au.e[j] = (_Float16)0.f;
        }
#pragma unroll
        for (int t = 0; t < NT; t++) {
            f16x8 bf = *reinterpret_cast<const f16x8*>(Wt + (t * 16 + m) * 128 + k0);
            acc[t] = __builtin_amdgcn_mfma_f32_16x16x32_f16(au.v, bf, acc[t], 0, 0, 0);
        }
    }
    // epilogue: scale by dinv[row], stage in LDS, store coalesced
#pragma unroll
    for (int r = 0; r < 4; r++) {
        int lrow = wave * 16 + q * 4 + r;
        int gr = grow0 + lrow;
        float s = (gr < NN) ? dinv[gr] : 0.f;
#pragma unroll
        for (int t = 0; t < NT; t++)
            Yl[lrow][t * 16 + m] = (_Float16)(s * acc[t][r]);
    }
    __syncthreads();
    constexpr int CH = F / 8;   // f16x8 chunks per row
    for (int i = tid; i < 64 * CH; i += 256) {
        int lrow = i / CH, c = i % CH;
        int gr = grow0 + lrow;
        if (gr < NN)
            *reinterpret_cast<f16x8*>(Yh + (size_t)gr * F + c * 8) =
                *reinterpret_cast<const f16x8*>(&Yl[lrow][c * 8]);
    }
}

// -------- Aggregate: out[v] = dinv[v]*sum_e XWh[col[e]] + b  (rows pre-scaled) ----

template <int F, bool RELU, typename OT>
__global__ __launch_bounds__(256) void aggregate_h(const __half* __restrict__ XWh,
                                                   const int* __restrict__ rowptr,
                                                   const int* __restrict__ col,
                                                   const float* __restrict__ dinv,
                                                   const float* __restrict__ bias,
                                                   OT* __restrict__ out) {
    constexpr int TPN = F / 8;
    constexpr int NPB = 256 / TPN;
    const int v = blockIdx.x * NPB + threadIdx.x / TPN;
    const int f = threadIdx.x % TPN;
    const int beg = rowptr[v];
    const int end = rowptr[v + 1];
    const float4* base = reinterpret_cast<const float4*>(XWh);
    float acc[8] = {0.f, 0.f, 0.f, 0.f, 0.f, 0.f, 0.f, 0.f};
#pragma unroll 4
    for (int e = beg; e < end; e++) {
        int u = col[e];
        float4 raw = base[(size_t)u * TPN + f];
        const __half2* h2 = reinterpret_cast<const __half2*>(&raw);
#pragma unroll
        for (int q = 0; q < 4; q++) {
            float2 fv = __half22float2(h2[q]);
            acc[2 * q]     += fv.x;
            acc[2 * q + 1] += fv.y;
        }
    }
    const float dv = dinv[v];
    float r[8];
#pragma unroll
    for (int q = 0; q < 8; q++) {
        r[q] = dv * acc[q] + bias[f * 8 + q];
        if (RELU) r[q] = fmaxf(r[q], 0.f);
    }
    if constexpr (sizeof(OT) == 2) {
        union { f16x8 v; _Float16 e[8]; } hu;
#pragma unroll
        for (int q = 0; q < 8; q++) hu.e[q] = (_Float16)r[q];
        *reinterpret_cast<f16x8*>((__half*)out + (size_t)v * F + f * 8) = hu.v;
    } else {
        float* op = (float*)out + (size_t)v * F + f * 8;
        *reinterpret_cast<float4*>(op)     = make_float4(r[0], r[1], r[2], r[3]);
        *reinterpret_cast<float4*>(op + 4) = make_float4(r[4], r[5], r[6], r[7]);
    }
}

// ---------------- launch ----------------

extern "C" void kernel_launch(void* const* d_in, const int* in_sizes, int n_in,
                              void* d_out, int out_size, void* d_ws, size_t ws_size,
                              hipStream_t stream) {
    const float* x  = (const float*)d_in[0];
    const int*   ei = (const int*)d_in[1];
    const float* W1 = (const float*)d_in[2];
    const float* b1 = (const float*)d_in[3];
    const float* W2 = (const float*)d_in[4];
    const float* b2 = (const float*)d_in[5];
    const float* W3 = (const float*)d_in[6];
    const float* b3 = (const float*)d_in[7];
    float* out = (float*)d_out;

    char* p = (char*)d_ws;
    int*      rowptr  = (int*)p;       p += 400016;
    float*    dinv    = (float*)p;     p += 400000;
    int*      gbc     = (int*)p;       p += 1024;
    int*      bbase   = (int*)p;       p += 1024;
    int*      gcursor = (int*)p;       p += 1024;
    _Float16* Wt1     = (_Float16*)p;  p += 32768;
    _Float16* Wt2     = (_Float16*)p;  p += 32768;
    _Float16* Wt3     = (_Float16*)p;  p += 16384;
    int*      part    = (int*)p;       p += (size_t)TT * 4;       // 6.8 MB
    int*      col     = (int*)p;       p += (size_t)TT * 4;       // 6.8 MB
    __half*   xwh     = (__half*)p;    p += (size_t)NN * 128 * 2; // 25.6 MB
    __half*   h       = (__half*)p;                                // 25.6 MB

    hipMemsetAsync(gbc, 0, NBUCK * 4, stream);
    wt_conv_all<<<160, 256, 0, stream>>>(W1, W2, W3, Wt1, Wt2, Wt3);
    bucket_count<<<NPB1, 256, 0, stream>>>(ei, gbc);
    scan_buckets<<<1, 256, 0, stream>>>(gbc, bbase, gcursor, rowptr);
    partition_p1<<<NPB1, 256, 0, stream>>>(ei, gcursor, part);
    partition_p2<<<NBUCK, 256, 0, stream>>>(part, bbase, rowptr, dinv, col);

    const int gb = (NN + 63) / 64;   // 1563
    // layer 1 (A fp32)
    gemm_mfma<128, false><<<gb, 256, 0, stream>>>(x, Wt1, dinv, xwh);
    aggregate_h<128, true, __half><<<NN / 16, 256, 0, stream>>>(
        xwh, rowptr, col, dinv, b1, h);
    // layer 2 (A fp16)
    gemm_mfma<128, true><<<gb, 256, 0, stream>>>(h, Wt2, dinv, xwh);
    aggregate_h<128, true, __half><<<NN / 16, 256, 0, stream>>>(
        xwh, rowptr, col, dinv, b2, h);
    // layer 3 (A fp16, no relu, fp32 out) -> d_out
    gemm_mfma<64, true><<<gb, 256, 0, stream>>>(h, Wt3, dinv, xwh);
    aggregate_h<64, false, float><<<NN / 32, 256, 0, stream>>>(
        xwh, rowptr, col, dinv, b3, out);
}